// Round 1
// baseline (213.016 us; speedup 1.0000x reference)
//
#include <hip/hip_runtime.h>
#include <hip/hip_bf16.h>

// ---- problem constants ----
#define BB 8
#define TT 4096
#define DD 512
#define MM (BB*TT)          // 32768 rows
#define DECAYF 0.95f
#define OMDECAYF (1.0f - 0.95f)

typedef __attribute__((ext_vector_type(8))) short bf16x8;
typedef __attribute__((ext_vector_type(4))) float f32x4;

__device__ __forceinline__ float gelu_f(float x){
  return 0.5f * x * (1.0f + erff(x * 0.70710678118654752f));
}

__device__ __forceinline__ unsigned short f2bf(float x){
  unsigned u = __float_as_uint(x);
  unsigned r = (u + 0x7FFFu + ((u >> 16) & 1u)) >> 16;
  return (unsigned short)r;
}

// =============== prep: spk_ctx, s_vec, coarse scalar (per batch) ===============
__global__ __launch_bounds__(256) void prep_kernel(
    const float* __restrict__ spk_embed, const float* __restrict__ spk_W,
    const float* __restrict__ spk_b, const float* __restrict__ cW1,
    const float* __restrict__ cb1, const float* __restrict__ cW2,
    const float* __restrict__ cb2, const float* __restrict__ rW1,
    const float* __restrict__ grate,
    float* __restrict__ s_vec, float* __restrict__ coarse_s)
{
  __shared__ float sc[DD];
  __shared__ float hid[DD];
  __shared__ float red[256];
  int b = blockIdx.x, t = threadIdx.x;
  for (int d = t; d < DD; d += 256){
    float a = spk_b[d];
    for (int k = 0; k < DD; ++k) a += spk_embed[b*DD + k] * spk_W[k*DD + d];
    sc[d] = tanhf(a);
  }
  __syncthreads();
  float grcv = grate[b];
  for (int d = t; d < DD; d += 256){
    float a1 = 0.f;
    float a2 = cb1[d] + grcv * cW1[DD*DD + d];   // row 512 of coarse_W1 = grc coeff
    for (int k = 0; k < DD; ++k){
      float s = sc[k];
      a1 += s * rW1[(DD + k)*DD + d];            // Ws = res_W1[D:2D]
      a2 += s * cW1[k*DD + d];
    }
    s_vec[b*DD + d] = a1;
    hid[d] = gelu_f(a2);
  }
  __syncthreads();
  float loc = 0.f;
  for (int d = t; d < DD; d += 256) loc += hid[d] * cW2[d];
  red[t] = loc;
  __syncthreads();
  for (int s = 128; s > 0; s >>= 1){ if (t < s) red[t] += red[t + s]; __syncthreads(); }
  if (t == 0) coarse_s[b] = 0.2f * tanhf(red[0] + cb2[0]);
}

// =============== transpose Wq (k-major f32) -> WqT (n-major bf16) ===============
__global__ __launch_bounds__(512) void transpose_kernel(
    const float* __restrict__ rW1, unsigned short* __restrict__ wqt)
{
  __shared__ float tile[64][65];
  int tx = threadIdx.x, ty = threadIdx.y;      // (64,8)
  int kb = blockIdx.y * 64, nb = blockIdx.x * 64;
  #pragma unroll
  for (int i = 0; i < 8; ++i){
    int k = ty + i*8;
    tile[k][tx] = rW1[(long)(kb + k)*DD + nb + tx];
  }
  __syncthreads();
  #pragma unroll
  for (int i = 0; i < 8; ++i){
    int nl = ty + i*8;
    wqt[(long)(nb + nl)*DD + kb + tx] = f2bf(tile[tx][nl]);
  }
}

// =============== affine scan: rate_seq + exclusive speech prefix ===============
__global__ __launch_bounds__(64) void scan_kernel(
    const float* __restrict__ la_g, const int* __restrict__ um,
    const int* __restrict__ sm, const int* __restrict__ zm,
    const float* __restrict__ lre,
    float* __restrict__ rate_seq, float* __restrict__ prefix)
{
  int b = blockIdx.x, l = threadIdx.x;
  int base = b*TT + l*64;
  float init = lre[b];
  float A = 1.f, Bv = 0.f, S = 0.f;
  for (int i = 0; i < 64; ++i){
    int t = base + i;
    float m = um[t] > 0 ? 1.f : 0.f;
    float sealed = sm[t] > 0 ? 1.f : 0.f;
    float sil = (zm[t] > 0 ? 1.f : 0.f) * m;
    float speech = (m * sealed) * (1.f - sil);
    if (speech > 0.f){
      Bv = DECAYF*Bv + OMDECAYF*la_g[t];
      A *= DECAYF;
      S += 1.f;
    }
  }
  // inclusive scan of affine composition across lanes (lane0 = earliest chunk)
  for (int d = 1; d < 64; d <<= 1){
    float Au = __shfl_up(A, d, 64);
    float Bu = __shfl_up(Bv, d, 64);
    float Su = __shfl_up(S, d, 64);
    if (l >= d){ Bv = A*Bu + Bv; A = A*Au; S += Su; }
  }
  float Ae = __shfl_up(A, 1, 64), Be = __shfl_up(Bv, 1, 64), Se = __shfl_up(S, 1, 64);
  if (l == 0){ Ae = 1.f; Be = 0.f; Se = 0.f; }
  float rate = Ae*init + Be;
  float ps = Se;
  for (int i = 0; i < 64; ++i){
    int t = base + i;
    rate_seq[t] = rate;
    prefix[t] = ps;
    float m = um[t] > 0 ? 1.f : 0.f;
    float sealed = sm[t] > 0 ? 1.f : 0.f;
    float sil = (zm[t] > 0 ? 1.f : 0.f) * m;
    float speech = (m * sealed) * (1.f - sil);
    if (speech > 0.f){
      rate = DECAYF*rate + OMDECAYF*la_g[t];
      ps += 1.f;
    }
  }
}

// =============== build Q (bf16) + per-row scalars ===============
__global__ __launch_bounds__(512) void build_q_kernel(
    const int* __restrict__ content, const float* __restrict__ la_g,
    const int* __restrict__ um, const int* __restrict__ sm, const int* __restrict__ zm,
    const float* __restrict__ sep, const float* __restrict__ edge,
    const float* __restrict__ stab_g, const float* __restrict__ grate,
    const float* __restrict__ emb, const float* __restrict__ fW, const float* __restrict__ fb,
    const float* __restrict__ rate_seq, const float* __restrict__ prefix,
    const float* __restrict__ coarse_s,
    unsigned short* __restrict__ wsQ,
    float* __restrict__ gterm_a, float* __restrict__ rgate_a,
    float* __restrict__ speech_a, float* __restrict__ silc_a)
{
  int wid = threadIdx.x >> 6, lane = threadIdx.x & 63;
  long gr = (long)blockIdx.x * 8 + wid;
  int b = (int)(gr >> 12);
  float la = la_g[gr];
  float m = um[gr] > 0 ? 1.f : 0.f;
  float sealed = sm[gr] > 0 ? 1.f : 0.f;
  float sil = (zm[gr] > 0 ? 1.f : 0.f) * m;
  float stab = fminf(fmaxf(stab_g[gr], 0.f), 1.f) * m;
  float commit = m * sealed;
  float silc = commit * sil;
  float speech = commit * (1.f - sil);
  float rate = rate_seq[gr];
  float gterm = (grate[b] - rate + coarse_s[b]) * commit;
  if (lane == 0){
    float cold = fminf(prefix[gr] * 0.5f, 1.f);                  // COLD_RUNS=2
    float shortg = fminf(fmaxf(expf(la) - 1.f, 0.f), 1.f);       // MIN_DUR=2
    gterm_a[gr] = gterm;
    rgate_a[gr] = cold * shortg * stab * speech;
    speech_a[gr] = speech;
    silc_a[gr] = silc;
  }
  float sepv = sep[gr], edgev = edge[gr];
  int c0 = lane * 8;
  const float* er = emb + (long)content[gr] * DD + c0;
  float4 e0 = *(const float4*)(er), e1 = *(const float4*)(er + 4);
  float ev[8] = {e0.x,e0.y,e0.z,e0.w,e1.x,e1.y,e1.z,e1.w};
  float wv[5][8];
  #pragma unroll
  for (int f = 0; f < 5; ++f){
    float4 a = *(const float4*)(fW + f*DD + c0);
    float4 bq = *(const float4*)(fW + f*DD + c0 + 4);
    wv[f][0]=a.x; wv[f][1]=a.y; wv[f][2]=a.z; wv[f][3]=a.w;
    wv[f][4]=bq.x; wv[f][5]=bq.y; wv[f][6]=bq.z; wv[f][7]=bq.w;
  }
  float4 fb0 = *(const float4*)(fb + c0), fb1 = *(const float4*)(fb + c0 + 4);
  float bv[8] = {fb0.x,fb0.y,fb0.z,fb0.w,fb1.x,fb1.y,fb1.z,fb1.w};
  union { bf16x8 v; unsigned short h[8]; } pk;
  #pragma unroll
  for (int i = 0; i < 8; ++i){
    float val = ev[i] + la*wv[0][i] + rate*wv[1][i] + sil*wv[2][i]
              + sepv*wv[3][i] + edgev*wv[4][i] + bv[i];
    pk.h[i] = f2bf(gelu_f(val) * m);
  }
  *(bf16x8*)(wsQ + gr*DD + c0) = pk.v;
}

// =============== fused GEMM + epilogue ===============
// BM=64, BN=512 (full N -> row-dot stays block-local), BK=32, 8 waves x (64x64)
__global__ __launch_bounds__(512, 4) void gemm_kernel(
    const unsigned short* __restrict__ wsQ, const unsigned short* __restrict__ wqt,
    const float* __restrict__ s_vec, const float* __restrict__ rW1,
    const float* __restrict__ rb1, const float* __restrict__ rW2,
    const float* __restrict__ rb2,
    const float* __restrict__ gterm_a, const float* __restrict__ rgate_a,
    const float* __restrict__ speech_a, const float* __restrict__ silc_a,
    float* __restrict__ out)
{
  __shared__ unsigned short As[2][64*32];    // 8 KB
  __shared__ unsigned short Bs[2][512*32];   // 64 KB
  __shared__ float part[8][64];              // 2 KB
  int tid = threadIdx.x, wid = tid >> 6, lane = tid & 63;
  int r0 = blockIdx.x * 64;
  int b = r0 >> 12;
  const char* qbase = (const char*)wsQ;
  const char* wbase = (const char*)wqt;

  // stage one BK=32 chunk into buffer `buf`. LDS dest is LINEAR; the XOR
  // slot-swizzle is applied on the GLOBAL source (and again on ds_read) so
  // it's a both-sides involution (rule #21).
  auto stage = [&](int buf, int kc){
    int k0b = kc * 64;  // byte offset into each 1024B (512-elem bf16) row
    #pragma unroll
    for (int i = 0; i < 4; ++i){
      int j = wid*4 + i;                      // 32 wave-issues for 512 n-rows
      int n = j*16 + (lane >> 2);
      int slot = (lane & 3) ^ ((n >> 1) & 3);
      const char* src = wbase + (long)n*1024 + k0b + slot*16;
      char* dst = (char*)&Bs[buf][0] + j*1024 + (lane << 4);
      __builtin_amdgcn_global_load_lds(
          (const __attribute__((address_space(1))) void*)src,
          (__attribute__((address_space(3))) void*)dst, 16, 0, 0);
    }
    if (wid < 4){
      int mrow = wid*16 + (lane >> 2);
      int slot = (lane & 3) ^ ((mrow >> 1) & 3);
      const char* src = qbase + (long)(r0 + mrow)*1024 + k0b + slot*16;
      char* dst = (char*)&As[buf][0] + wid*1024 + (lane << 4);
      __builtin_amdgcn_global_load_lds(
          (const __attribute__((address_space(1))) void*)src,
          (__attribute__((address_space(3))) void*)dst, 16, 0, 0);
    }
  };

  f32x4 acc[4][4];
  #pragma unroll
  for (int i = 0; i < 4; ++i)
    #pragma unroll
    for (int j = 0; j < 4; ++j) acc[i][j] = (f32x4){0.f,0.f,0.f,0.f};

  stage(0, 0);
  __syncthreads();
  int rg = lane >> 4, li = lane & 15;
  for (int kc = 0; kc < 16; ++kc){
    int cur = kc & 1;
    if (kc < 15) stage(cur ^ 1, kc + 1);
    bf16x8 a[4], bb[4];
    #pragma unroll
    for (int mt = 0; mt < 4; ++mt){
      int row = mt*16 + li;
      int slot = rg ^ ((row >> 1) & 3);
      a[mt] = *(const bf16x8*)((const char*)&As[cur][0] + row*64 + slot*16);
    }
    #pragma unroll
    for (int nt = 0; nt < 4; ++nt){
      int n = wid*64 + nt*16 + li;
      int slot = rg ^ ((n >> 1) & 3);
      bb[nt] = *(const bf16x8*)((const char*)&Bs[cur][0] + n*64 + slot*16);
    }
    #pragma unroll
    for (int mt = 0; mt < 4; ++mt)
      #pragma unroll
      for (int nt = 0; nt < 4; ++nt)
        acc[mt][nt] = __builtin_amdgcn_mfma_f32_16x16x32_bf16(a[mt], bb[nt], acc[mt][nt], 0, 0, 0);
    __syncthreads();
  }

  // epilogue: h = gelu(y + s_vec + gterm*wg + b1); partial dot with res_W2
  float sv[4], wgv[4], b1v[4], w2v[4];
  #pragma unroll
  for (int nt = 0; nt < 4; ++nt){
    int j = wid*64 + nt*16 + li;
    sv[nt]  = s_vec[b*DD + j];
    wgv[nt] = rW1[1024*DD + j];    // wg = res_W1 row 1024
    b1v[nt] = rb1[j];
    w2v[nt] = rW2[j];
  }
  #pragma unroll
  for (int mt = 0; mt < 4; ++mt){
    #pragma unroll
    for (int r = 0; r < 4; ++r){
      int row = mt*16 + rg*4 + r;
      float gt = gterm_a[r0 + row];
      float s = 0.f;
      #pragma unroll
      for (int nt = 0; nt < 4; ++nt){
        float y = acc[mt][nt][r] + sv[nt] + gt*wgv[nt] + b1v[nt];
        s += gelu_f(y) * w2v[nt];
      }
      s += __shfl_xor(s, 1, 64);
      s += __shfl_xor(s, 2, 64);
      s += __shfl_xor(s, 4, 64);
      s += __shfl_xor(s, 8, 64);
      if (li == 0) part[wid][row] = s;
    }
  }
  __syncthreads();
  if (tid < 64){
    int gr = r0 + tid;
    float s = 0.f;
    #pragma unroll
    for (int w = 0; w < 8; ++w) s += part[w][tid];
    float resid = 0.35f * tanhf(s + rb2[0]) * rgate_a[gr];
    float g = gterm_a[gr];
    float ps = fminf(fmaxf(g + resid, -1.2f), 1.2f) * speech_a[gr];
    float pz = fminf(fmaxf(g, -0.35f), 0.35f) * silc_a[gr];
    out[gr] = ps + pz;
  }
}

extern "C" void kernel_launch(void* const* d_in, const int* in_sizes, int n_in,
                              void* d_out, int out_size, void* d_ws, size_t ws_size,
                              hipStream_t stream)
{
  const int*   content = (const int*)  d_in[0];
  const float* la      = (const float*)d_in[1];
  const int*   um      = (const int*)  d_in[2];
  const int*   smk     = (const int*)  d_in[3];
  const int*   zm      = (const int*)  d_in[4];
  const float* sep     = (const float*)d_in[5];
  const float* edge    = (const float*)d_in[6];
  const float* stab    = (const float*)d_in[7];
  const float* grate   = (const float*)d_in[8];
  const float* lre     = (const float*)d_in[9];
  const float* spk_e   = (const float*)d_in[10];
  const float* emb     = (const float*)d_in[11];
  const float* fW      = (const float*)d_in[12];
  const float* fb      = (const float*)d_in[13];
  const float* spk_W   = (const float*)d_in[14];
  const float* spk_b   = (const float*)d_in[15];
  const float* cW1     = (const float*)d_in[16];
  const float* cb1     = (const float*)d_in[17];
  const float* cW2     = (const float*)d_in[18];
  const float* cb2     = (const float*)d_in[19];
  const float* rW1     = (const float*)d_in[20];
  const float* rb1     = (const float*)d_in[21];
  const float* rW2     = (const float*)d_in[22];
  const float* rb2     = (const float*)d_in[23];

  char* w = (char*)d_ws;
  unsigned short* wsQ   = (unsigned short*)(w);                        // 32768*512*2 = 33554432 B
  unsigned short* wsWqT = (unsigned short*)(w + 33554432);             // 512*512*2   = 524288 B
  size_t off = 33554432 + 524288;
  float* rate_seq = (float*)(w + off); off += MM*4;
  float* prefix   = (float*)(w + off); off += MM*4;
  float* gterm_a  = (float*)(w + off); off += MM*4;
  float* rgate_a  = (float*)(w + off); off += MM*4;
  float* speech_a = (float*)(w + off); off += MM*4;
  float* silc_a   = (float*)(w + off); off += MM*4;
  float* s_vec    = (float*)(w + off); off += BB*DD*4;
  float* coarse_s = (float*)(w + off); off += 256;

  prep_kernel<<<BB, 256, 0, stream>>>(spk_e, spk_W, spk_b, cW1, cb1, cW2, cb2, rW1,
                                      grate, s_vec, coarse_s);
  transpose_kernel<<<dim3(8,8), dim3(64,8), 0, stream>>>(rW1, wsWqT);
  scan_kernel<<<BB, 64, 0, stream>>>(la, um, smk, zm, lre, rate_seq, prefix);
  build_q_kernel<<<MM/8, 512, 0, stream>>>(content, la, um, smk, zm, sep, edge, stab,
      grate, emb, fW, fb, rate_seq, prefix, coarse_s, wsQ,
      gterm_a, rgate_a, speech_a, silc_a);
  gemm_kernel<<<MM/64, 512, 0, stream>>>(wsQ, wsWqT, s_vec, rW1, rb1, rW2, rb2,
      gterm_a, rgate_a, speech_a, silc_a, (float*)d_out);
}

// Round 3
// 127.411 us; speedup vs baseline: 1.6719x; 1.6719x over previous
//
#include <hip/hip_runtime.h>
#include <hip/hip_bf16.h>

// ---- problem constants ----
#define BB 8
#define TT 4096
#define DD 512
#define MM (BB*TT)          // 32768 rows
#define DECAYF 0.95f
#define OMDECAYF (1.0f - 0.95f)

typedef __attribute__((ext_vector_type(8))) short bf16x8;
typedef __attribute__((ext_vector_type(4))) float f32x4;

__device__ __forceinline__ float gelu_f(float x){
  return 0.5f * x * (1.0f + erff(x * 0.70710678118654752f));
}

__device__ __forceinline__ unsigned short f2bf(float x){
  unsigned u = __float_as_uint(x);
  unsigned r = (u + 0x7FFFu + ((u >> 16) & 1u)) >> 16;
  return (unsigned short)r;
}

// =============== prep1: spk_ctx = tanh(spk_embed @ spk_W + spk_b) ===============
// grid 64 = b*8 + d-chunk(64); block 512 = 8 k-slices x 64 d
__global__ __launch_bounds__(512) void prep1_kernel(
    const float* __restrict__ spk_embed, const float* __restrict__ spk_W,
    const float* __restrict__ spk_b, float* __restrict__ spk_ctx)
{
  __shared__ float se[DD];
  __shared__ float red[8][64];
  int blk = blockIdx.x;
  int b = blk >> 3, d0 = (blk & 7) * 64;
  int t = threadIdx.x, dl = t & 63, ks = t >> 6;
  se[t] = spk_embed[b*DD + t];
  __syncthreads();
  float a = 0.f;
  const float* wp = spk_W + (long)(ks*64)*DD + d0 + dl;
  #pragma unroll 8
  for (int k = 0; k < 64; ++k) a += se[ks*64 + k] * wp[(long)k*DD];
  red[ks][dl] = a;
  __syncthreads();
  if (t < 64){
    float s = spk_b[d0 + t];
    #pragma unroll
    for (int i = 0; i < 8; ++i) s += red[i][t];
    spk_ctx[b*DD + d0 + t] = tanhf(s);
  }
}

// =============== prep2: s_vec = spk_ctx@Ws ; coarse hidden partial dot ===============
__global__ __launch_bounds__(512) void prep2_kernel(
    const float* __restrict__ spk_ctx, const float* __restrict__ rW1,
    const float* __restrict__ cW1, const float* __restrict__ cb1,
    const float* __restrict__ cW2, const float* __restrict__ grate,
    float* __restrict__ s_vec, float* __restrict__ coarse_part)
{
  __shared__ float sc[DD];
  __shared__ float red1[8][64];
  __shared__ float red2[8][64];
  int blk = blockIdx.x;
  int b = blk >> 3, d0 = (blk & 7) * 64;
  int t = threadIdx.x, dl = t & 63, ks = t >> 6;
  sc[t] = spk_ctx[b*DD + t];
  __syncthreads();
  float a1 = 0.f, a2 = 0.f;
  const float* wsp = rW1 + (long)(DD + ks*64)*DD + d0 + dl;   // Ws = res_W1[D:2D]
  const float* wcp = cW1 + (long)(ks*64)*DD + d0 + dl;
  #pragma unroll 4
  for (int k = 0; k < 64; ++k){
    float s = sc[ks*64 + k];
    a1 += s * wsp[(long)k*DD];
    a2 += s * wcp[(long)k*DD];
  }
  red1[ks][dl] = a1; red2[ks][dl] = a2;
  __syncthreads();
  if (t < 64){
    int d = d0 + t;
    float s1 = 0.f;
    float s2 = cb1[d] + grate[b] * cW1[(long)DD*DD + d];   // row 512 = grc coeff
    #pragma unroll
    for (int i = 0; i < 8; ++i){ s1 += red1[i][t]; s2 += red2[i][t]; }
    s_vec[b*DD + d] = s1;
    float hv = gelu_f(s2) * cW2[d];
    #pragma unroll
    for (int sh = 1; sh < 64; sh <<= 1) hv += __shfl_xor(hv, sh, 64);
    if (t == 0) coarse_part[blk] = hv;
  }
}

// =============== prep3: coarse scalar ===============
__global__ __launch_bounds__(64) void prep3_kernel(
    const float* __restrict__ coarse_part, const float* __restrict__ cb2,
    float* __restrict__ coarse_s)
{
  int t = threadIdx.x;
  if (t < BB){
    float s = cb2[0];
    #pragma unroll
    for (int c = 0; c < 8; ++c) s += coarse_part[t*8 + c];
    coarse_s[t] = 0.2f * tanhf(s);
  }
}

// =============== transpose Wq (k-major f32) -> WqT (n-major bf16) ===============
__global__ __launch_bounds__(512) void transpose_kernel(
    const float* __restrict__ rW1, unsigned short* __restrict__ wqt)
{
  __shared__ float tile[64][65];
  int tx = threadIdx.x, ty = threadIdx.y;      // (64,8)
  int kb = blockIdx.y * 64, nb = blockIdx.x * 64;
  #pragma unroll
  for (int i = 0; i < 8; ++i){
    int k = ty + i*8;
    tile[k][tx] = rW1[(long)(kb + k)*DD + nb + tx];
  }
  __syncthreads();
  #pragma unroll
  for (int i = 0; i < 8; ++i){
    int nl = ty + i*8;
    wqt[(long)(nb + nl)*DD + kb + tx] = f2bf(tile[tx][nl]);
  }
}

// =============== affine scan: rate_seq + exclusive speech prefix ===============
__global__ __launch_bounds__(64) void scan_kernel(
    const float* __restrict__ la_g, const int* __restrict__ um,
    const int* __restrict__ sm, const int* __restrict__ zm,
    const float* __restrict__ lre,
    float* __restrict__ rate_seq, float* __restrict__ prefix)
{
  int b = blockIdx.x, l = threadIdx.x;
  int base = b*TT + l*64;
  float init = lre[b];
  float A = 1.f, Bv = 0.f, S = 0.f;
  for (int i = 0; i < 64; ++i){
    int t = base + i;
    float m = um[t] > 0 ? 1.f : 0.f;
    float sealed = sm[t] > 0 ? 1.f : 0.f;
    float sil = (zm[t] > 0 ? 1.f : 0.f) * m;
    float speech = (m * sealed) * (1.f - sil);
    if (speech > 0.f){
      Bv = DECAYF*Bv + OMDECAYF*la_g[t];
      A *= DECAYF;
      S += 1.f;
    }
  }
  for (int d = 1; d < 64; d <<= 1){
    float Au = __shfl_up(A, d, 64);
    float Bu = __shfl_up(Bv, d, 64);
    float Su = __shfl_up(S, d, 64);
    if (l >= d){ Bv = A*Bu + Bv; A = A*Au; S += Su; }
  }
  float Ae = __shfl_up(A, 1, 64), Be = __shfl_up(Bv, 1, 64), Se = __shfl_up(S, 1, 64);
  if (l == 0){ Ae = 1.f; Be = 0.f; Se = 0.f; }
  float rate = Ae*init + Be;
  float ps = Se;
  for (int i = 0; i < 64; ++i){
    int t = base + i;
    rate_seq[t] = rate;
    prefix[t] = ps;
    float m = um[t] > 0 ? 1.f : 0.f;
    float sealed = sm[t] > 0 ? 1.f : 0.f;
    float sil = (zm[t] > 0 ? 1.f : 0.f) * m;
    float speech = (m * sealed) * (1.f - sil);
    if (speech > 0.f){
      rate = DECAYF*rate + OMDECAYF*la_g[t];
      ps += 1.f;
    }
  }
}

// =============== build Q (bf16) + per-row scalars ===============
__global__ __launch_bounds__(512) void build_q_kernel(
    const int* __restrict__ content, const float* __restrict__ la_g,
    const int* __restrict__ um, const int* __restrict__ sm, const int* __restrict__ zm,
    const float* __restrict__ sep, const float* __restrict__ edge,
    const float* __restrict__ stab_g, const float* __restrict__ grate,
    const float* __restrict__ emb, const float* __restrict__ fW, const float* __restrict__ fb,
    const float* __restrict__ rate_seq, const float* __restrict__ prefix,
    const float* __restrict__ coarse_s,
    unsigned short* __restrict__ wsQ,
    float* __restrict__ gterm_a, float* __restrict__ rgate_a,
    float* __restrict__ speech_a, float* __restrict__ silc_a)
{
  int wid = threadIdx.x >> 6, lane = threadIdx.x & 63;
  long gr = (long)blockIdx.x * 8 + wid;
  int b = (int)(gr >> 12);
  float la = la_g[gr];
  float m = um[gr] > 0 ? 1.f : 0.f;
  float sealed = sm[gr] > 0 ? 1.f : 0.f;
  float sil = (zm[gr] > 0 ? 1.f : 0.f) * m;
  float stab = fminf(fmaxf(stab_g[gr], 0.f), 1.f) * m;
  float commit = m * sealed;
  float silc = commit * sil;
  float speech = commit * (1.f - sil);
  float rate = rate_seq[gr];
  float gterm = (grate[b] - rate + coarse_s[b]) * commit;
  if (lane == 0){
    float cold = fminf(prefix[gr] * 0.5f, 1.f);                  // COLD_RUNS=2
    float shortg = fminf(fmaxf(expf(la) - 1.f, 0.f), 1.f);       // MIN_DUR=2
    gterm_a[gr] = gterm;
    rgate_a[gr] = cold * shortg * stab * speech;
    speech_a[gr] = speech;
    silc_a[gr] = silc;
  }
  float sepv = sep[gr], edgev = edge[gr];
  int c0 = lane * 8;
  const float* er = emb + (long)content[gr] * DD + c0;
  float4 e0 = *(const float4*)(er), e1 = *(const float4*)(er + 4);
  float ev[8] = {e0.x,e0.y,e0.z,e0.w,e1.x,e1.y,e1.z,e1.w};
  float wv[5][8];
  #pragma unroll
  for (int f = 0; f < 5; ++f){
    float4 a = *(const float4*)(fW + f*DD + c0);
    float4 bq = *(const float4*)(fW + f*DD + c0 + 4);
    wv[f][0]=a.x; wv[f][1]=a.y; wv[f][2]=a.z; wv[f][3]=a.w;
    wv[f][4]=bq.x; wv[f][5]=bq.y; wv[f][6]=bq.z; wv[f][7]=bq.w;
  }
  float4 fb0 = *(const float4*)(fb + c0), fb1 = *(const float4*)(fb + c0 + 4);
  float bv[8] = {fb0.x,fb0.y,fb0.z,fb0.w,fb1.x,fb1.y,fb1.z,fb1.w};
  union { bf16x8 v; unsigned short h[8]; } pk;
  #pragma unroll
  for (int i = 0; i < 8; ++i){
    float val = ev[i] + la*wv[0][i] + rate*wv[1][i] + sil*wv[2][i]
              + sepv*wv[3][i] + edgev*wv[4][i] + bv[i];
    pk.h[i] = f2bf(gelu_f(val) * m);
  }
  *(bf16x8*)(wsQ + gr*DD + c0) = pk.v;
}

// =============== fused GEMM + epilogue ===============
// BM=64, BN=512 (full N -> row-dot stays block-local), BK=32, 8 waves x (64x64)
__global__ __launch_bounds__(512, 4) void gemm_kernel(
    const unsigned short* __restrict__ wsQ, const unsigned short* __restrict__ wqt,
    const float* __restrict__ s_vec, const float* __restrict__ rW1,
    const float* __restrict__ rb1, const float* __restrict__ rW2,
    const float* __restrict__ rb2,
    const float* __restrict__ gterm_a, const float* __restrict__ rgate_a,
    const float* __restrict__ speech_a, const float* __restrict__ silc_a,
    float* __restrict__ out)
{
  __shared__ unsigned short As[2][64*32];    // 8 KB
  __shared__ unsigned short Bs[2][512*32];   // 64 KB
  __shared__ float part[8][64];              // 2 KB
  int tid = threadIdx.x, wid = tid >> 6, lane = tid & 63;
  int r0 = blockIdx.x * 64;
  int b = r0 >> 12;
  const char* qbase = (const char*)wsQ;
  const char* wbase = (const char*)wqt;

  auto stage = [&](int buf, int kc){
    int k0b = kc * 64;  // byte offset into each 1024B (512-elem bf16) row
    #pragma unroll
    for (int i = 0; i < 4; ++i){
      int j = wid*4 + i;
      int n = j*16 + (lane >> 2);
      int slot = (lane & 3) ^ ((n >> 1) & 3);
      const char* src = wbase + (long)n*1024 + k0b + slot*16;
      char* dst = (char*)&Bs[buf][0] + j*1024 + (lane << 4);
      __builtin_amdgcn_global_load_lds(
          (const __attribute__((address_space(1))) void*)src,
          (__attribute__((address_space(3))) void*)dst, 16, 0, 0);
    }
    if (wid < 4){
      int mrow = wid*16 + (lane >> 2);
      int slot = (lane & 3) ^ ((mrow >> 1) & 3);
      const char* src = qbase + (long)(r0 + mrow)*1024 + k0b + slot*16;
      char* dst = (char*)&As[buf][0] + wid*1024 + (lane << 4);
      __builtin_amdgcn_global_load_lds(
          (const __attribute__((address_space(1))) void*)src,
          (__attribute__((address_space(3))) void*)dst, 16, 0, 0);
    }
  };

  f32x4 acc[4][4];
  #pragma unroll
  for (int i = 0; i < 4; ++i)
    #pragma unroll
    for (int j = 0; j < 4; ++j) acc[i][j] = (f32x4){0.f,0.f,0.f,0.f};

  stage(0, 0);
  __syncthreads();
  int rg = lane >> 4, li = lane & 15;
  for (int kc = 0; kc < 16; ++kc){
    int cur = kc & 1;
    if (kc < 15) stage(cur ^ 1, kc + 1);
    bf16x8 a[4], bb[4];
    #pragma unroll
    for (int mt = 0; mt < 4; ++mt){
      int row = mt*16 + li;
      int slot = rg ^ ((row >> 1) & 3);
      a[mt] = *(const bf16x8*)((const char*)&As[cur][0] + row*64 + slot*16);
    }
    #pragma unroll
    for (int nt = 0; nt < 4; ++nt){
      int n = wid*64 + nt*16 + li;
      int slot = rg ^ ((n >> 1) & 3);
      bb[nt] = *(const bf16x8*)((const char*)&Bs[cur][0] + n*64 + slot*16);
    }
    #pragma unroll
    for (int mt = 0; mt < 4; ++mt)
      #pragma unroll
      for (int nt = 0; nt < 4; ++nt)
        acc[mt][nt] = __builtin_amdgcn_mfma_f32_16x16x32_bf16(a[mt], bb[nt], acc[mt][nt], 0, 0, 0);
    __syncthreads();
  }

  float sv[4], wgv[4], b1v[4], w2v[4];
  #pragma unroll
  for (int nt = 0; nt < 4; ++nt){
    int j = wid*64 + nt*16 + li;
    sv[nt]  = s_vec[b*DD + j];
    wgv[nt] = rW1[1024*DD + j];    // wg = res_W1 row 1024
    b1v[nt] = rb1[j];
    w2v[nt] = rW2[j];
  }
  #pragma unroll
  for (int mt = 0; mt < 4; ++mt){
    #pragma unroll
    for (int r = 0; r < 4; ++r){
      int row = mt*16 + rg*4 + r;
      float gt = gterm_a[r0 + row];
      float s = 0.f;
      #pragma unroll
      for (int nt = 0; nt < 4; ++nt){
        float y = acc[mt][nt][r] + sv[nt] + gt*wgv[nt] + b1v[nt];
        s += gelu_f(y) * w2v[nt];
      }
      s += __shfl_xor(s, 1, 64);
      s += __shfl_xor(s, 2, 64);
      s += __shfl_xor(s, 4, 64);
      s += __shfl_xor(s, 8, 64);
      if (li == 0) part[wid][row] = s;
    }
  }
  __syncthreads();
  if (tid < 64){
    int gr = r0 + tid;
    float s = 0.f;
    #pragma unroll
    for (int w = 0; w < 8; ++w) s += part[w][tid];
    float resid = 0.35f * tanhf(s + rb2[0]) * rgate_a[gr];
    float g = gterm_a[gr];
    float ps = fminf(fmaxf(g + resid, -1.2f), 1.2f) * speech_a[gr];
    float pz = fminf(fmaxf(g, -0.35f), 0.35f) * silc_a[gr];
    out[gr] = ps + pz;
  }
}

extern "C" void kernel_launch(void* const* d_in, const int* in_sizes, int n_in,
                              void* d_out, int out_size, void* d_ws, size_t ws_size,
                              hipStream_t stream)
{
  const int*   content = (const int*)  d_in[0];
  const float* la      = (const float*)d_in[1];
  const int*   um      = (const int*)  d_in[2];
  const int*   smk     = (const int*)  d_in[3];
  const int*   zm      = (const int*)  d_in[4];
  const float* sep     = (const float*)d_in[5];
  const float* edge    = (const float*)d_in[6];
  const float* stab    = (const float*)d_in[7];
  const float* grate   = (const float*)d_in[8];
  const float* lre     = (const float*)d_in[9];
  const float* spk_e   = (const float*)d_in[10];
  const float* emb     = (const float*)d_in[11];
  const float* fW      = (const float*)d_in[12];
  const float* fb      = (const float*)d_in[13];
  const float* spk_W   = (const float*)d_in[14];
  const float* spk_b   = (const float*)d_in[15];
  const float* cW1     = (const float*)d_in[16];
  const float* cb1     = (const float*)d_in[17];
  const float* cW2     = (const float*)d_in[18];
  const float* cb2     = (const float*)d_in[19];
  const float* rW1     = (const float*)d_in[20];
  const float* rb1     = (const float*)d_in[21];
  const float* rW2     = (const float*)d_in[22];
  const float* rb2     = (const float*)d_in[23];

  char* w = (char*)d_ws;
  unsigned short* wsQ   = (unsigned short*)(w);                        // 33554432 B
  unsigned short* wsWqT = (unsigned short*)(w + 33554432);             // 524288 B
  size_t off = 33554432 + 524288;
  float* rate_seq = (float*)(w + off); off += MM*4;
  float* prefix   = (float*)(w + off); off += MM*4;
  float* gterm_a  = (float*)(w + off); off += MM*4;
  float* rgate_a  = (float*)(w + off); off += MM*4;
  float* speech_a = (float*)(w + off); off += MM*4;
  float* silc_a   = (float*)(w + off); off += MM*4;
  float* s_vec    = (float*)(w + off); off += BB*DD*4;
  float* coarse_s = (float*)(w + off); off += 256;
  float* spk_ctx  = (float*)(w + off); off += BB*DD*4;
  float* coarse_part = (float*)(w + off); off += 64*4;

  prep1_kernel<<<64, 512, 0, stream>>>(spk_e, spk_W, spk_b, spk_ctx);
  prep2_kernel<<<64, 512, 0, stream>>>(spk_ctx, rW1, cW1, cb1, cW2, grate,
                                       s_vec, coarse_part);
  prep3_kernel<<<1, 64, 0, stream>>>(coarse_part, cb2, coarse_s);
  transpose_kernel<<<dim3(8,8), dim3(64,8), 0, stream>>>(rW1, wsWqT);
  scan_kernel<<<BB, 64, 0, stream>>>(la, um, smk, zm, lre, rate_seq, prefix);
  build_q_kernel<<<MM/8, 512, 0, stream>>>(content, la, um, smk, zm, sep, edge, stab,
      grate, emb, fW, fb, rate_seq, prefix, coarse_s, wsQ,
      gterm_a, rgate_a, speech_a, silc_a);
  gemm_kernel<<<MM/64, 512, 0, stream>>>(wsQ, wsWqT, s_vec, rW1, rb1, rW2, rb2,
      gterm_a, rgate_a, speech_a, silc_a, (float*)d_out);
}

// Round 4
// 85.972 us; speedup vs baseline: 2.4777x; 1.4820x over previous
//
#include <hip/hip_runtime.h>
#include <hip/hip_bf16.h>

// ---- problem constants ----
#define BB 8
#define TT 4096
#define DD 512
#define MM (BB*TT)          // 32768 rows
#define DECAYF 0.95f
#define OMDECAYF (1.0f - 0.95f)

typedef __attribute__((ext_vector_type(8))) short bf16x8;
typedef __attribute__((ext_vector_type(4))) float f32x4;

__device__ __forceinline__ float gelu_f(float x){
  return 0.5f * x * (1.0f + erff(x * 0.70710678118654752f));
}

__device__ __forceinline__ unsigned short f2bf(float x){
  unsigned u = __float_as_uint(x);
  unsigned r = (u + 0x7FFFu + ((u >> 16) & 1u)) >> 16;
  return (unsigned short)r;
}

// =============== prep1: spk_ctx = tanh(spk_embed @ spk_W + spk_b) ===============
__global__ __launch_bounds__(512) void prep1_kernel(
    const float* __restrict__ spk_embed, const float* __restrict__ spk_W,
    const float* __restrict__ spk_b, float* __restrict__ spk_ctx)
{
  __shared__ float se[DD];
  __shared__ float red[8][64];
  int blk = blockIdx.x;
  int b = blk >> 3, d0 = (blk & 7) * 64;
  int t = threadIdx.x, dl = t & 63, ks = t >> 6;
  se[t] = spk_embed[b*DD + t];
  __syncthreads();
  float a = 0.f;
  const float* wp = spk_W + (long)(ks*64)*DD + d0 + dl;
  #pragma unroll 8
  for (int k = 0; k < 64; ++k) a += se[ks*64 + k] * wp[(long)k*DD];
  red[ks][dl] = a;
  __syncthreads();
  if (t < 64){
    float s = spk_b[d0 + t];
    #pragma unroll
    for (int i = 0; i < 8; ++i) s += red[i][t];
    spk_ctx[b*DD + d0 + t] = tanhf(s);
  }
}

// =============== prep2: s_vec = spk_ctx@Ws ; coarse hidden partial dot ===============
__global__ __launch_bounds__(512) void prep2_kernel(
    const float* __restrict__ spk_ctx, const float* __restrict__ rW1,
    const float* __restrict__ cW1, const float* __restrict__ cb1,
    const float* __restrict__ cW2, const float* __restrict__ grate,
    float* __restrict__ s_vec, float* __restrict__ coarse_part)
{
  __shared__ float sc[DD];
  __shared__ float red1[8][64];
  __shared__ float red2[8][64];
  int blk = blockIdx.x;
  int b = blk >> 3, d0 = (blk & 7) * 64;
  int t = threadIdx.x, dl = t & 63, ks = t >> 6;
  sc[t] = spk_ctx[b*DD + t];
  __syncthreads();
  float a1 = 0.f, a2 = 0.f;
  const float* wsp = rW1 + (long)(DD + ks*64)*DD + d0 + dl;   // Ws = res_W1[D:2D]
  const float* wcp = cW1 + (long)(ks*64)*DD + d0 + dl;
  #pragma unroll 4
  for (int k = 0; k < 64; ++k){
    float s = sc[ks*64 + k];
    a1 += s * wsp[(long)k*DD];
    a2 += s * wcp[(long)k*DD];
  }
  red1[ks][dl] = a1; red2[ks][dl] = a2;
  __syncthreads();
  if (t < 64){
    int d = d0 + t;
    float s1 = 0.f;
    float s2 = cb1[d] + grate[b] * cW1[(long)DD*DD + d];   // row 512 = grc coeff
    #pragma unroll
    for (int i = 0; i < 8; ++i){ s1 += red1[i][t]; s2 += red2[i][t]; }
    s_vec[b*DD + d] = s1;
    float hv = gelu_f(s2) * cW2[d];
    #pragma unroll
    for (int sh = 1; sh < 64; sh <<= 1) hv += __shfl_xor(hv, sh, 64);
    if (t == 0) coarse_part[blk] = hv;
  }
}

// =============== prep3: coarse scalar ===============
__global__ __launch_bounds__(64) void prep3_kernel(
    const float* __restrict__ coarse_part, const float* __restrict__ cb2,
    float* __restrict__ coarse_s)
{
  int t = threadIdx.x;
  if (t < BB){
    float s = cb2[0];
    #pragma unroll
    for (int c = 0; c < 8; ++c) s += coarse_part[t*8 + c];
    coarse_s[t] = 0.2f * tanhf(s);
  }
}

// =============== transpose Wq (k-major f32) -> WqT (n-major bf16) ===============
__global__ __launch_bounds__(512) void transpose_kernel(
    const float* __restrict__ rW1, unsigned short* __restrict__ wqt)
{
  __shared__ float tile[64][65];
  int tx = threadIdx.x, ty = threadIdx.y;      // (64,8)
  int kb = blockIdx.y * 64, nb = blockIdx.x * 64;
  #pragma unroll
  for (int i = 0; i < 8; ++i){
    int k = ty + i*8;
    tile[k][tx] = rW1[(long)(kb + k)*DD + nb + tx];
  }
  __syncthreads();
  #pragma unroll
  for (int i = 0; i < 8; ++i){
    int nl = ty + i*8;
    wqt[(long)(nb + nl)*DD + kb + tx] = f2bf(tile[tx][nl]);
  }
}

// =============== hierarchical affine scan: rate_seq + exclusive speech prefix ===
// one block per batch; 512 threads x 8 elements; thread-fold -> wave shfl scan
// -> cross-wave LDS scan -> apply
__global__ __launch_bounds__(512) void scan_kernel(
    const float* __restrict__ la_g, const int* __restrict__ um,
    const int* __restrict__ sm, const int* __restrict__ zm,
    const float* __restrict__ lre,
    float* __restrict__ rate_seq, float* __restrict__ prefix)
{
  __shared__ float wAg[8], wBg[8], wSg[8];
  int b = blockIdx.x, t = threadIdx.x;
  int lane = t & 63, wid = t >> 6;
  int base = b*TT + t*8;

  float4 la0 = *(const float4*)(la_g + base);
  float4 la1 = *(const float4*)(la_g + base + 4);
  int4 u0 = *(const int4*)(um + base), u1 = *(const int4*)(um + base + 4);
  int4 s0 = *(const int4*)(sm + base), s1 = *(const int4*)(sm + base + 4);
  int4 z0 = *(const int4*)(zm + base), z1 = *(const int4*)(zm + base + 4);
  float lav[8] = {la0.x,la0.y,la0.z,la0.w,la1.x,la1.y,la1.z,la1.w};
  int uv[8] = {u0.x,u0.y,u0.z,u0.w,u1.x,u1.y,u1.z,u1.w};
  int sv[8] = {s0.x,s0.y,s0.z,s0.w,s1.x,s1.y,s1.z,s1.w};
  int zv[8] = {z0.x,z0.y,z0.z,z0.w,z1.x,z1.y,z1.z,z1.w};
  float spv[8];

  float A = 1.f, Bv = 0.f, S = 0.f;
  #pragma unroll
  for (int i = 0; i < 8; ++i){
    float m = uv[i] > 0 ? 1.f : 0.f;
    float sealed = sv[i] > 0 ? 1.f : 0.f;
    float sil = (zv[i] > 0 ? 1.f : 0.f) * m;
    float speech = (m * sealed) * (1.f - sil);
    spv[i] = speech;
    if (speech > 0.f){
      Bv = DECAYF*Bv + OMDECAYF*lav[i];
      A *= DECAYF;
      S += 1.f;
    }
  }
  // wave-inclusive scan (lane order = time order)
  #pragma unroll
  for (int d = 1; d < 64; d <<= 1){
    float Au = __shfl_up(A, d, 64);
    float Bu = __shfl_up(Bv, d, 64);
    float Su = __shfl_up(S, d, 64);
    if (lane >= d){ Bv = A*Bu + Bv; A = A*Au; S += Su; }
  }
  if (lane == 63){ wAg[wid] = A; wBg[wid] = Bv; wSg[wid] = S; }
  // lane-exclusive within wave
  float Ale = __shfl_up(A, 1, 64), Ble = __shfl_up(Bv, 1, 64), Sle = __shfl_up(S, 1, 64);
  if (lane == 0){ Ale = 1.f; Ble = 0.f; Sle = 0.f; }
  __syncthreads();
  // exclusive prefix over earlier waves (<=7 LDS reads, serial compose)
  float Awp = 1.f, Bwp = 0.f, Swp = 0.f;
  for (int w = 0; w < wid; ++w){
    Bwp = wAg[w]*Bwp + wBg[w];
    Awp = wAg[w]*Awp;
    Swp += wSg[w];
  }
  // total thread-exclusive = waveprefix then lane-exclusive
  float Bex = Ale*Bwp + Ble;
  float Aex = Ale*Awp;
  float Sex = Swp + Sle;

  float rate = Aex*lre[b] + Bex;
  float ps = Sex;
  float ro[8], po[8];
  #pragma unroll
  for (int i = 0; i < 8; ++i){
    ro[i] = rate; po[i] = ps;
    if (spv[i] > 0.f){
      rate = DECAYF*rate + OMDECAYF*lav[i];
      ps += 1.f;
    }
  }
  *(float4*)(rate_seq + base)     = make_float4(ro[0],ro[1],ro[2],ro[3]);
  *(float4*)(rate_seq + base + 4) = make_float4(ro[4],ro[5],ro[6],ro[7]);
  *(float4*)(prefix + base)       = make_float4(po[0],po[1],po[2],po[3]);
  *(float4*)(prefix + base + 4)   = make_float4(po[4],po[5],po[6],po[7]);
}

// =============== build Q (bf16) + per-row scalars ===============
__global__ __launch_bounds__(512) void build_q_kernel(
    const int* __restrict__ content, const float* __restrict__ la_g,
    const int* __restrict__ um, const int* __restrict__ sm, const int* __restrict__ zm,
    const float* __restrict__ sep, const float* __restrict__ edge,
    const float* __restrict__ stab_g, const float* __restrict__ grate,
    const float* __restrict__ emb, const float* __restrict__ fW, const float* __restrict__ fb,
    const float* __restrict__ rate_seq, const float* __restrict__ prefix,
    const float* __restrict__ coarse_s,
    unsigned short* __restrict__ wsQ,
    float* __restrict__ gterm_a, float* __restrict__ rgate_a,
    float* __restrict__ speech_a, float* __restrict__ silc_a)
{
  int wid = threadIdx.x >> 6, lane = threadIdx.x & 63;
  long gr = (long)blockIdx.x * 8 + wid;
  int b = (int)(gr >> 12);
  float la = la_g[gr];
  float m = um[gr] > 0 ? 1.f : 0.f;
  float sealed = sm[gr] > 0 ? 1.f : 0.f;
  float sil = (zm[gr] > 0 ? 1.f : 0.f) * m;
  float stab = fminf(fmaxf(stab_g[gr], 0.f), 1.f) * m;
  float commit = m * sealed;
  float silc = commit * sil;
  float speech = commit * (1.f - sil);
  float rate = rate_seq[gr];
  float gterm = (grate[b] - rate + coarse_s[b]) * commit;
  if (lane == 0){
    float cold = fminf(prefix[gr] * 0.5f, 1.f);                  // COLD_RUNS=2
    float shortg = fminf(fmaxf(expf(la) - 1.f, 0.f), 1.f);       // MIN_DUR=2
    gterm_a[gr] = gterm;
    rgate_a[gr] = cold * shortg * stab * speech;
    speech_a[gr] = speech;
    silc_a[gr] = silc;
  }
  float sepv = sep[gr], edgev = edge[gr];
  int c0 = lane * 8;
  const float* er = emb + (long)content[gr] * DD + c0;
  float4 e0 = *(const float4*)(er), e1 = *(const float4*)(er + 4);
  float ev[8] = {e0.x,e0.y,e0.z,e0.w,e1.x,e1.y,e1.z,e1.w};
  float wv[5][8];
  #pragma unroll
  for (int f = 0; f < 5; ++f){
    float4 a = *(const float4*)(fW + f*DD + c0);
    float4 bq = *(const float4*)(fW + f*DD + c0 + 4);
    wv[f][0]=a.x; wv[f][1]=a.y; wv[f][2]=a.z; wv[f][3]=a.w;
    wv[f][4]=bq.x; wv[f][5]=bq.y; wv[f][6]=bq.z; wv[f][7]=bq.w;
  }
  float4 fb0 = *(const float4*)(fb + c0), fb1 = *(const float4*)(fb + c0 + 4);
  float bv[8] = {fb0.x,fb0.y,fb0.z,fb0.w,fb1.x,fb1.y,fb1.z,fb1.w};
  union { bf16x8 v; unsigned short h[8]; } pk;
  #pragma unroll
  for (int i = 0; i < 8; ++i){
    float val = ev[i] + la*wv[0][i] + rate*wv[1][i] + sil*wv[2][i]
              + sepv*wv[3][i] + edgev*wv[4][i] + bv[i];
    pk.h[i] = f2bf(gelu_f(val) * m);
  }
  *(bf16x8*)(wsQ + gr*DD + c0) = pk.v;
}

// =============== fused GEMM + epilogue ===============
// BM=64, BN=512 (full N -> row-dot stays block-local), BK=32, 8 waves x (64x64)
__global__ __launch_bounds__(512, 4) void gemm_kernel(
    const unsigned short* __restrict__ wsQ, const unsigned short* __restrict__ wqt,
    const float* __restrict__ s_vec, const float* __restrict__ rW1,
    const float* __restrict__ rb1, const float* __restrict__ rW2,
    const float* __restrict__ rb2,
    const float* __restrict__ gterm_a, const float* __restrict__ rgate_a,
    const float* __restrict__ speech_a, const float* __restrict__ silc_a,
    float* __restrict__ out)
{
  __shared__ unsigned short As[2][64*32];    // 8 KB
  __shared__ unsigned short Bs[2][512*32];   // 64 KB
  __shared__ float part[8][64];              // 2 KB
  int tid = threadIdx.x, wid = tid >> 6, lane = tid & 63;
  int r0 = blockIdx.x * 64;
  int b = r0 >> 12;
  const char* qbase = (const char*)wsQ;
  const char* wbase = (const char*)wqt;

  auto stage = [&](int buf, int kc){
    int k0b = kc * 64;  // byte offset into each 1024B (512-elem bf16) row
    #pragma unroll
    for (int i = 0; i < 4; ++i){
      int j = wid*4 + i;
      int n = j*16 + (lane >> 2);
      int slot = (lane & 3) ^ ((n >> 1) & 3);
      const char* src = wbase + (long)n*1024 + k0b + slot*16;
      char* dst = (char*)&Bs[buf][0] + j*1024 + (lane << 4);
      __builtin_amdgcn_global_load_lds(
          (const __attribute__((address_space(1))) void*)src,
          (__attribute__((address_space(3))) void*)dst, 16, 0, 0);
    }
    if (wid < 4){
      int mrow = wid*16 + (lane >> 2);
      int slot = (lane & 3) ^ ((mrow >> 1) & 3);
      const char* src = qbase + (long)(r0 + mrow)*1024 + k0b + slot*16;
      char* dst = (char*)&As[buf][0] + wid*1024 + (lane << 4);
      __builtin_amdgcn_global_load_lds(
          (const __attribute__((address_space(1))) void*)src,
          (__attribute__((address_space(3))) void*)dst, 16, 0, 0);
    }
  };

  f32x4 acc[4][4];
  #pragma unroll
  for (int i = 0; i < 4; ++i)
    #pragma unroll
    for (int j = 0; j < 4; ++j) acc[i][j] = (f32x4){0.f,0.f,0.f,0.f};

  stage(0, 0);
  __syncthreads();
  int rg = lane >> 4, li = lane & 15;
  for (int kc = 0; kc < 16; ++kc){
    int cur = kc & 1;
    if (kc < 15) stage(cur ^ 1, kc + 1);
    bf16x8 a[4], bb[4];
    #pragma unroll
    for (int mt = 0; mt < 4; ++mt){
      int row = mt*16 + li;
      int slot = rg ^ ((row >> 1) & 3);
      a[mt] = *(const bf16x8*)((const char*)&As[cur][0] + row*64 + slot*16);
    }
    #pragma unroll
    for (int nt = 0; nt < 4; ++nt){
      int n = wid*64 + nt*16 + li;
      int slot = rg ^ ((n >> 1) & 3);
      bb[nt] = *(const bf16x8*)((const char*)&Bs[cur][0] + n*64 + slot*16);
    }
    #pragma unroll
    for (int mt = 0; mt < 4; ++mt)
      #pragma unroll
      for (int nt = 0; nt < 4; ++nt)
        acc[mt][nt] = __builtin_amdgcn_mfma_f32_16x16x32_bf16(a[mt], bb[nt], acc[mt][nt], 0, 0, 0);
    __syncthreads();
  }

  float sv[4], wgv[4], b1v[4], w2v[4];
  #pragma unroll
  for (int nt = 0; nt < 4; ++nt){
    int j = wid*64 + nt*16 + li;
    sv[nt]  = s_vec[b*DD + j];
    wgv[nt] = rW1[1024*DD + j];    // wg = res_W1 row 1024
    b1v[nt] = rb1[j];
    w2v[nt] = rW2[j];
  }
  #pragma unroll
  for (int mt = 0; mt < 4; ++mt){
    #pragma unroll
    for (int r = 0; r < 4; ++r){
      int row = mt*16 + rg*4 + r;
      float gt = gterm_a[r0 + row];
      float s = 0.f;
      #pragma unroll
      for (int nt = 0; nt < 4; ++nt){
        float y = acc[mt][nt][r] + sv[nt] + gt*wgv[nt] + b1v[nt];
        s += gelu_f(y) * w2v[nt];
      }
      s += __shfl_xor(s, 1, 64);
      s += __shfl_xor(s, 2, 64);
      s += __shfl_xor(s, 4, 64);
      s += __shfl_xor(s, 8, 64);
      if (li == 0) part[wid][row] = s;
    }
  }
  __syncthreads();
  if (tid < 64){
    int gr = r0 + tid;
    float s = 0.f;
    #pragma unroll
    for (int w = 0; w < 8; ++w) s += part[w][tid];
    float resid = 0.35f * tanhf(s + rb2[0]) * rgate_a[gr];
    float g = gterm_a[gr];
    float ps = fminf(fmaxf(g + resid, -1.2f), 1.2f) * speech_a[gr];
    float pz = fminf(fmaxf(g, -0.35f), 0.35f) * silc_a[gr];
    out[gr] = ps + pz;
  }
}

extern "C" void kernel_launch(void* const* d_in, const int* in_sizes, int n_in,
                              void* d_out, int out_size, void* d_ws, size_t ws_size,
                              hipStream_t stream)
{
  const int*   content = (const int*)  d_in[0];
  const float* la      = (const float*)d_in[1];
  const int*   um      = (const int*)  d_in[2];
  const int*   smk     = (const int*)  d_in[3];
  const int*   zm      = (const int*)  d_in[4];
  const float* sep     = (const float*)d_in[5];
  const float* edge    = (const float*)d_in[6];
  const float* stab    = (const float*)d_in[7];
  const float* grate   = (const float*)d_in[8];
  const float* lre     = (const float*)d_in[9];
  const float* spk_e   = (const float*)d_in[10];
  const float* emb     = (const float*)d_in[11];
  const float* fW      = (const float*)d_in[12];
  const float* fb      = (const float*)d_in[13];
  const float* spk_W   = (const float*)d_in[14];
  const float* spk_b   = (const float*)d_in[15];
  const float* cW1     = (const float*)d_in[16];
  const float* cb1     = (const float*)d_in[17];
  const float* cW2     = (const float*)d_in[18];
  const float* cb2     = (const float*)d_in[19];
  const float* rW1     = (const float*)d_in[20];
  const float* rb1     = (const float*)d_in[21];
  const float* rW2     = (const float*)d_in[22];
  const float* rb2     = (const float*)d_in[23];

  char* w = (char*)d_ws;
  unsigned short* wsQ   = (unsigned short*)(w);                        // 33554432 B
  unsigned short* wsWqT = (unsigned short*)(w + 33554432);             // 524288 B
  size_t off = 33554432 + 524288;
  float* rate_seq = (float*)(w + off); off += MM*4;
  float* prefix   = (float*)(w + off); off += MM*4;
  float* gterm_a  = (float*)(w + off); off += MM*4;
  float* rgate_a  = (float*)(w + off); off += MM*4;
  float* speech_a = (float*)(w + off); off += MM*4;
  float* silc_a   = (float*)(w + off); off += MM*4;
  float* s_vec    = (float*)(w + off); off += BB*DD*4;
  float* coarse_s = (float*)(w + off); off += 256;
  float* spk_ctx  = (float*)(w + off); off += BB*DD*4;
  float* coarse_part = (float*)(w + off); off += 64*4;

  prep1_kernel<<<64, 512, 0, stream>>>(spk_e, spk_W, spk_b, spk_ctx);
  prep2_kernel<<<64, 512, 0, stream>>>(spk_ctx, rW1, cW1, cb1, cW2, grate,
                                       s_vec, coarse_part);
  prep3_kernel<<<1, 64, 0, stream>>>(coarse_part, cb2, coarse_s);
  transpose_kernel<<<dim3(8,8), dim3(64,8), 0, stream>>>(rW1, wsWqT);
  scan_kernel<<<BB, 512, 0, stream>>>(la, um, smk, zm, lre, rate_seq, prefix);
  build_q_kernel<<<MM/8, 512, 0, stream>>>(content, la, um, smk, zm, sep, edge, stab,
      grate, emb, fW, fb, rate_seq, prefix, coarse_s, wsQ,
      gterm_a, rgate_a, speech_a, silc_a);
  gemm_kernel<<<MM/64, 512, 0, stream>>>(wsQ, wsWqT, s_vec, rW1, rb1, rW2, rb2,
      gterm_a, rgate_a, speech_a, silc_a, (float*)d_out);
}

// Round 5
// 52.972 us; speedup vs baseline: 4.0213x; 1.6230x over previous
//
#include <hip/hip_runtime.h>
#include <hip/hip_bf16.h>

// ---- problem constants ----
#define BB 8
#define TT 4096
#define DD 512
#define MM (BB*TT)          // 32768 rows
#define DECAYF 0.95f
#define OMDECAYF (1.0f - 0.95f)

typedef __attribute__((ext_vector_type(8))) short bf16x8;
typedef __attribute__((ext_vector_type(4))) float f32x4;

__device__ __forceinline__ float gelu_f(float x){
  return 0.5f * x * (1.0f + erff(x * 0.70710678118654752f));
}

__device__ __forceinline__ unsigned short f2bf(float x){
  unsigned u = __float_as_uint(x);
  unsigned r = (u + 0x7FFFu + ((u >> 16) & 1u)) >> 16;
  return (unsigned short)r;
}

// =============== prep1: spk_ctx = tanh(spk_embed @ spk_W + spk_b) ===============
__global__ __launch_bounds__(512) void prep1_kernel(
    const float* __restrict__ spk_embed, const float* __restrict__ spk_W,
    const float* __restrict__ spk_b, float* __restrict__ spk_ctx)
{
  __shared__ float se[DD];
  __shared__ float red[8][64];
  int blk = blockIdx.x;
  int b = blk >> 3, d0 = (blk & 7) * 64;
  int t = threadIdx.x, dl = t & 63, ks = t >> 6;
  se[t] = spk_embed[b*DD + t];
  __syncthreads();
  float a = 0.f;
  const float* wp = spk_W + (long)(ks*64)*DD + d0 + dl;
  #pragma unroll 8
  for (int k = 0; k < 64; ++k) a += se[ks*64 + k] * wp[(long)k*DD];
  red[ks][dl] = a;
  __syncthreads();
  if (t < 64){
    float s = spk_b[d0 + t];
    #pragma unroll
    for (int i = 0; i < 8; ++i) s += red[i][t];
    spk_ctx[b*DD + d0 + t] = tanhf(s);
  }
}

// =============== prep2: s_vec = spk_ctx@Ws ; coarse hidden partial dot ===============
__global__ __launch_bounds__(512) void prep2_kernel(
    const float* __restrict__ spk_ctx, const float* __restrict__ rW1,
    const float* __restrict__ cW1, const float* __restrict__ cb1,
    const float* __restrict__ cW2, const float* __restrict__ grate,
    float* __restrict__ s_vec, float* __restrict__ coarse_part)
{
  __shared__ float sc[DD];
  __shared__ float red1[8][64];
  __shared__ float red2[8][64];
  int blk = blockIdx.x;
  int b = blk >> 3, d0 = (blk & 7) * 64;
  int t = threadIdx.x, dl = t & 63, ks = t >> 6;
  sc[t] = spk_ctx[b*DD + t];
  __syncthreads();
  float a1 = 0.f, a2 = 0.f;
  const float* wsp = rW1 + (long)(DD + ks*64)*DD + d0 + dl;   // Ws = res_W1[D:2D]
  const float* wcp = cW1 + (long)(ks*64)*DD + d0 + dl;
  #pragma unroll 4
  for (int k = 0; k < 64; ++k){
    float s = sc[ks*64 + k];
    a1 += s * wsp[(long)k*DD];
    a2 += s * wcp[(long)k*DD];
  }
  red1[ks][dl] = a1; red2[ks][dl] = a2;
  __syncthreads();
  if (t < 64){
    int d = d0 + t;
    float s1 = 0.f;
    float s2 = cb1[d] + grate[b] * cW1[(long)DD*DD + d];   // row 512 = grc coeff
    #pragma unroll
    for (int i = 0; i < 8; ++i){ s1 += red1[i][t]; s2 += red2[i][t]; }
    s_vec[b*DD + d] = s1;
    float hv = gelu_f(s2) * cW2[d];
    #pragma unroll
    for (int sh = 1; sh < 64; sh <<= 1) hv += __shfl_xor(hv, sh, 64);
    if (t == 0) coarse_part[blk] = hv;
  }
}

// =============== prep3: coarse scalar ===============
__global__ __launch_bounds__(64) void prep3_kernel(
    const float* __restrict__ coarse_part, const float* __restrict__ cb2,
    float* __restrict__ coarse_s)
{
  int t = threadIdx.x;
  if (t < BB){
    float s = cb2[0];
    #pragma unroll
    for (int c = 0; c < 8; ++c) s += coarse_part[t*8 + c];
    coarse_s[t] = 0.2f * tanhf(s);
  }
}

// =============== transpose Wq (k-major f32) -> WqT (n-major bf16) ===============
__global__ __launch_bounds__(512) void transpose_kernel(
    const float* __restrict__ rW1, unsigned short* __restrict__ wqt)
{
  __shared__ float tile[64][65];
  int tx = threadIdx.x, ty = threadIdx.y;      // (64,8)
  int kb = blockIdx.y * 64, nb = blockIdx.x * 64;
  #pragma unroll
  for (int i = 0; i < 8; ++i){
    int k = ty + i*8;
    tile[k][tx] = rW1[(long)(kb + k)*DD + nb + tx];
  }
  __syncthreads();
  #pragma unroll
  for (int i = 0; i < 8; ++i){
    int nl = ty + i*8;
    wqt[(long)(nb + nl)*DD + kb + tx] = f2bf(tile[tx][nl]);
  }
}

// === fused scan: rate + prefix + gterm/rgate + baseline out + active compaction ===
// one block per batch; 512 threads x 8 elements
__global__ __launch_bounds__(512) void scan_kernel(
    const float* __restrict__ la_g, const int* __restrict__ um,
    const int* __restrict__ sm, const int* __restrict__ zm,
    const float* __restrict__ stab_g, const float* __restrict__ lre,
    const float* __restrict__ grate, const float* __restrict__ coarse_s,
    float* __restrict__ rate_seq, float* __restrict__ gterm_a,
    float* __restrict__ rgate_a, int* __restrict__ active_list,
    unsigned* __restrict__ counter, float* __restrict__ out)
{
  __shared__ float wAg[8], wBg[8], wSg[8];
  int b = blockIdx.x, t = threadIdx.x;
  int lane = t & 63, wid = t >> 6;
  int base = b*TT + t*8;

  float4 la0 = *(const float4*)(la_g + base);
  float4 la1 = *(const float4*)(la_g + base + 4);
  int4 u0 = *(const int4*)(um + base), u1 = *(const int4*)(um + base + 4);
  int4 s0 = *(const int4*)(sm + base), s1 = *(const int4*)(sm + base + 4);
  int4 z0 = *(const int4*)(zm + base), z1 = *(const int4*)(zm + base + 4);
  float4 st0 = *(const float4*)(stab_g + base), st1 = *(const float4*)(stab_g + base + 4);
  float lav[8] = {la0.x,la0.y,la0.z,la0.w,la1.x,la1.y,la1.z,la1.w};
  int uv[8] = {u0.x,u0.y,u0.z,u0.w,u1.x,u1.y,u1.z,u1.w};
  int sv[8] = {s0.x,s0.y,s0.z,s0.w,s1.x,s1.y,s1.z,s1.w};
  int zv[8] = {z0.x,z0.y,z0.z,z0.w,z1.x,z1.y,z1.z,z1.w};
  float stv_[8] = {st0.x,st0.y,st0.z,st0.w,st1.x,st1.y,st1.z,st1.w};
  float spv[8], cmv[8], slv[8], stv[8];

  float A = 1.f, Bv = 0.f, S = 0.f;
  #pragma unroll
  for (int i = 0; i < 8; ++i){
    float m = uv[i] > 0 ? 1.f : 0.f;
    float sealed = sv[i] > 0 ? 1.f : 0.f;
    float sil = (zv[i] > 0 ? 1.f : 0.f) * m;
    float commit = m * sealed;
    float speech = commit * (1.f - sil);
    spv[i] = speech; cmv[i] = commit; slv[i] = commit * sil;
    stv[i] = fminf(fmaxf(stv_[i], 0.f), 1.f) * m;
    if (speech > 0.f){
      Bv = DECAYF*Bv + OMDECAYF*lav[i];
      A *= DECAYF;
      S += 1.f;
    }
  }
  // wave-inclusive scan (lane order = time order)
  #pragma unroll
  for (int d = 1; d < 64; d <<= 1){
    float Au = __shfl_up(A, d, 64);
    float Bu = __shfl_up(Bv, d, 64);
    float Su = __shfl_up(S, d, 64);
    if (lane >= d){ Bv = A*Bu + Bv; A = A*Au; S += Su; }
  }
  if (lane == 63){ wAg[wid] = A; wBg[wid] = Bv; wSg[wid] = S; }
  float Ale = __shfl_up(A, 1, 64), Ble = __shfl_up(Bv, 1, 64), Sle = __shfl_up(S, 1, 64);
  if (lane == 0){ Ale = 1.f; Ble = 0.f; Sle = 0.f; }
  __syncthreads();
  float Awp = 1.f, Bwp = 0.f, Swp = 0.f;
  for (int w = 0; w < wid; ++w){
    Bwp = wAg[w]*Bwp + wBg[w];
    Awp = wAg[w]*Awp;
    Swp += wSg[w];
  }
  float Bex = Ale*Bwp + Ble;
  float Aex = Ale*Awp;
  float Sex = Swp + Sle;

  float rate = Aex*lre[b] + Bex;
  float ps = Sex;
  float grc = grate[b], cs = coarse_s[b];
  float ro[8], go[8], rg[8], oo[8];
  #pragma unroll
  for (int i = 0; i < 8; ++i){
    ro[i] = rate;
    float g = (grc - rate + cs) * cmv[i];
    float cold = fminf(ps * 0.5f, 1.f);                       // COLD_RUNS=2
    float shortg = fminf(fmaxf(expf(lav[i]) - 1.f, 0.f), 1.f); // MIN_DUR=2
    float rgv = cold * shortg * stv[i] * spv[i];
    go[i] = g; rg[i] = rgv;
    oo[i] = fminf(fmaxf(g, -1.2f), 1.2f) * spv[i]
          + fminf(fmaxf(g, -0.35f), 0.35f) * slv[i];
    if (spv[i] > 0.f){
      rate = DECAYF*rate + OMDECAYF*lav[i];
      ps += 1.f;
    }
  }
  *(float4*)(rate_seq + base)     = make_float4(ro[0],ro[1],ro[2],ro[3]);
  *(float4*)(rate_seq + base + 4) = make_float4(ro[4],ro[5],ro[6],ro[7]);
  *(float4*)(gterm_a + base)      = make_float4(go[0],go[1],go[2],go[3]);
  *(float4*)(gterm_a + base + 4)  = make_float4(go[4],go[5],go[6],go[7]);
  *(float4*)(rgate_a + base)      = make_float4(rg[0],rg[1],rg[2],rg[3]);
  *(float4*)(rgate_a + base + 4)  = make_float4(rg[4],rg[5],rg[6],rg[7]);
  *(float4*)(out + base)          = make_float4(oo[0],oo[1],oo[2],oo[3]);
  *(float4*)(out + base + 4)      = make_float4(oo[4],oo[5],oo[6],oo[7]);

  // --- compaction: append active row indices (rgate != 0) ---
  int nact = 0;
  #pragma unroll
  for (int i = 0; i < 8; ++i) nact += (rg[i] != 0.f) ? 1 : 0;
  int inc = nact;
  #pragma unroll
  for (int d = 1; d < 64; d <<= 1){
    int u = __shfl_up(inc, d, 64);
    if (lane >= d) inc += u;
  }
  int myex = inc - nact;
  unsigned ub = 0;
  if (lane == 63) ub = atomicAdd(counter, (unsigned)inc);
  ub = (unsigned)__shfl((int)ub, 63, 64);
  int pos = (int)ub + myex;
  #pragma unroll
  for (int i = 0; i < 8; ++i){
    if (rg[i] != 0.f) active_list[pos++] = base + i;
  }
}

// =============== build Q (bf16) for ACTIVE rows only (compacted) ===============
// active rows have m=1, sealed=1, sil=0
__global__ __launch_bounds__(512) void build_q_kernel(
    const int* __restrict__ content, const float* __restrict__ la_g,
    const float* __restrict__ sep, const float* __restrict__ edge,
    const float* __restrict__ emb, const float* __restrict__ fW,
    const float* __restrict__ fb, const float* __restrict__ rate_seq,
    const int* __restrict__ active_list, const unsigned* __restrict__ counter,
    unsigned short* __restrict__ wsQ)
{
  int wid = threadIdx.x >> 6, lane = threadIdx.x & 63;
  int cnt = (int)*counter;
  int c0 = lane * 8;
  for (int p = blockIdx.x*8 + wid; p < cnt; p += gridDim.x*8){
    int gr = active_list[p];
    float la = la_g[gr], rate = rate_seq[gr];
    float sepv = sep[gr], edgev = edge[gr];
    const float* er = emb + (long)content[gr] * DD + c0;
    float4 e0 = *(const float4*)(er), e1 = *(const float4*)(er + 4);
    float ev[8] = {e0.x,e0.y,e0.z,e0.w,e1.x,e1.y,e1.z,e1.w};
    float wv[4][8];
    const int frow[4] = {0,1,3,4};   // skip silence row (sil=0 for active rows)
    #pragma unroll
    for (int f = 0; f < 4; ++f){
      float4 a = *(const float4*)(fW + frow[f]*DD + c0);
      float4 bq = *(const float4*)(fW + frow[f]*DD + c0 + 4);
      wv[f][0]=a.x; wv[f][1]=a.y; wv[f][2]=a.z; wv[f][3]=a.w;
      wv[f][4]=bq.x; wv[f][5]=bq.y; wv[f][6]=bq.z; wv[f][7]=bq.w;
    }
    float4 fb0 = *(const float4*)(fb + c0), fb1 = *(const float4*)(fb + c0 + 4);
    float bv[8] = {fb0.x,fb0.y,fb0.z,fb0.w,fb1.x,fb1.y,fb1.z,fb1.w};
    union { bf16x8 v; unsigned short h[8]; } pk;
    #pragma unroll
    for (int i = 0; i < 8; ++i){
      float val = ev[i] + la*wv[0][i] + rate*wv[1][i]
                + sepv*wv[2][i] + edgev*wv[3][i] + bv[i];
      pk.h[i] = f2bf(gelu_f(val));
    }
    *(bf16x8*)(wsQ + (long)p*DD + c0) = pk.v;
  }
}

// =============== fused GEMM + epilogue on ACTIVE rows ===============
// BM=32, BN=512 (full N -> row-dot block-local), BK=32, 8 waves x (32x64)
__global__ __launch_bounds__(512) void gemm_kernel(
    const unsigned short* __restrict__ wsQ, const unsigned short* __restrict__ wqt,
    const float* __restrict__ s_vec, const float* __restrict__ rW1,
    const float* __restrict__ rb1, const float* __restrict__ rW2,
    const float* __restrict__ rb2,
    const float* __restrict__ gterm_a, const float* __restrict__ rgate_a,
    const int* __restrict__ active_list, const unsigned* __restrict__ counter,
    float* __restrict__ out)
{
  __shared__ unsigned short As[2][32*32];    // 4 KB
  __shared__ unsigned short Bs[2][512*32];   // 64 KB
  __shared__ float part[8][32];              // 1 KB
  int tid = threadIdx.x, wid = tid >> 6, lane = tid & 63;
  int cnt = (int)*counter;
  int r0 = blockIdx.x * 32;
  if (r0 >= cnt) return;
  const char* qbase = (const char*)wsQ;
  const char* wbase = (const char*)wqt;

  auto stage = [&](int buf, int kc){
    int k0b = kc * 64;  // byte offset into each 1024B (512-elem bf16) row
    #pragma unroll
    for (int i = 0; i < 4; ++i){
      int j = wid*4 + i;                      // 32 wave-issues for 512 n-rows
      int n = j*16 + (lane >> 2);
      int slot = (lane & 3) ^ ((n >> 1) & 3);
      const char* src = wbase + (long)n*1024 + k0b + slot*16;
      char* dst = (char*)&Bs[buf][0] + j*1024 + (lane << 4);
      __builtin_amdgcn_global_load_lds(
          (const __attribute__((address_space(1))) void*)src,
          (__attribute__((address_space(3))) void*)dst, 16, 0, 0);
    }
    if (wid < 2){
      int mrow = wid*16 + (lane >> 2);
      int slot = (lane & 3) ^ ((mrow >> 1) & 3);
      const char* src = qbase + (long)(r0 + mrow)*1024 + k0b + slot*16;
      char* dst = (char*)&As[buf][0] + wid*1024 + (lane << 4);
      __builtin_amdgcn_global_load_lds(
          (const __attribute__((address_space(1))) void*)src,
          (__attribute__((address_space(3))) void*)dst, 16, 0, 0);
    }
  };

  f32x4 acc[2][4];
  #pragma unroll
  for (int i = 0; i < 2; ++i)
    #pragma unroll
    for (int j = 0; j < 4; ++j) acc[i][j] = (f32x4){0.f,0.f,0.f,0.f};

  stage(0, 0);
  __syncthreads();
  int rgp = lane >> 4, li = lane & 15;
  for (int kc = 0; kc < 16; ++kc){
    int cur = kc & 1;
    if (kc < 15) stage(cur ^ 1, kc + 1);
    bf16x8 a[2], bb[4];
    #pragma unroll
    for (int mt = 0; mt < 2; ++mt){
      int row = mt*16 + li;
      int slot = rgp ^ ((row >> 1) & 3);
      a[mt] = *(const bf16x8*)((const char*)&As[cur][0] + row*64 + slot*16);
    }
    #pragma unroll
    for (int nt = 0; nt < 4; ++nt){
      int n = wid*64 + nt*16 + li;
      int slot = rgp ^ ((n >> 1) & 3);
      bb[nt] = *(const bf16x8*)((const char*)&Bs[cur][0] + n*64 + slot*16);
    }
    #pragma unroll
    for (int mt = 0; mt < 2; ++mt)
      #pragma unroll
      for (int nt = 0; nt < 4; ++nt)
        acc[mt][nt] = __builtin_amdgcn_mfma_f32_16x16x32_bf16(a[mt], bb[nt], acc[mt][nt], 0, 0, 0);
    __syncthreads();
  }

  // epilogue: h = gelu(y + s_vec[b] + gterm*wg + b1); partial dot with res_W2
  float wgv[4], b1v[4], w2v[4];
  #pragma unroll
  for (int nt = 0; nt < 4; ++nt){
    int j = wid*64 + nt*16 + li;
    wgv[nt] = rW1[1024*DD + j];    // wg = res_W1 row 1024
    b1v[nt] = rb1[j];
    w2v[nt] = rW2[j];
  }
  #pragma unroll
  for (int mt = 0; mt < 2; ++mt){
    #pragma unroll
    for (int r = 0; r < 4; ++r){
      int row = mt*16 + rgp*4 + r;
      int p = r0 + row; if (p > cnt-1) p = cnt-1;
      int gr = active_list[p];
      int b = gr >> 12;
      float gt = gterm_a[gr];
      float s = 0.f;
      #pragma unroll
      for (int nt = 0; nt < 4; ++nt){
        int j = wid*64 + nt*16 + li;
        float y = acc[mt][nt][r] + s_vec[b*DD + j] + gt*wgv[nt] + b1v[nt];
        s += gelu_f(y) * w2v[nt];
      }
      s += __shfl_xor(s, 1, 64);
      s += __shfl_xor(s, 2, 64);
      s += __shfl_xor(s, 4, 64);
      s += __shfl_xor(s, 8, 64);
      if (li == 0) part[wid][row] = s;
    }
  }
  __syncthreads();
  if (tid < 32){
    int p = r0 + tid;
    if (p < cnt){
      int gr = active_list[p];
      float s = 0.f;
      #pragma unroll
      for (int w = 0; w < 8; ++w) s += part[w][tid];
      float resid = 0.35f * tanhf(s + rb2[0]) * rgate_a[gr];
      float g = gterm_a[gr];
      // active rows: speech==1, sil_commit==0
      out[gr] = fminf(fmaxf(g + resid, -1.2f), 1.2f);
    }
  }
}

extern "C" void kernel_launch(void* const* d_in, const int* in_sizes, int n_in,
                              void* d_out, int out_size, void* d_ws, size_t ws_size,
                              hipStream_t stream)
{
  const int*   content = (const int*)  d_in[0];
  const float* la      = (const float*)d_in[1];
  const int*   um      = (const int*)  d_in[2];
  const int*   smk     = (const int*)  d_in[3];
  const int*   zm      = (const int*)  d_in[4];
  const float* sep     = (const float*)d_in[5];
  const float* edge    = (const float*)d_in[6];
  const float* stab    = (const float*)d_in[7];
  const float* grate   = (const float*)d_in[8];
  const float* lre     = (const float*)d_in[9];
  const float* spk_e   = (const float*)d_in[10];
  const float* emb     = (const float*)d_in[11];
  const float* fW      = (const float*)d_in[12];
  const float* fb      = (const float*)d_in[13];
  const float* spk_W   = (const float*)d_in[14];
  const float* spk_b   = (const float*)d_in[15];
  const float* cW1     = (const float*)d_in[16];
  const float* cb1     = (const float*)d_in[17];
  const float* cW2     = (const float*)d_in[18];
  const float* cb2     = (const float*)d_in[19];
  const float* rW1     = (const float*)d_in[20];
  const float* rb1     = (const float*)d_in[21];
  const float* rW2     = (const float*)d_in[22];
  const float* rb2     = (const float*)d_in[23];

  char* w = (char*)d_ws;
  unsigned short* wsQ   = (unsigned short*)(w);                        // 33554432 B (worst case)
  unsigned short* wsWqT = (unsigned short*)(w + 33554432);             // 524288 B
  size_t off = 33554432 + 524288;
  float* rate_seq = (float*)(w + off); off += MM*4;
  float* gterm_a  = (float*)(w + off); off += MM*4;
  float* rgate_a  = (float*)(w + off); off += MM*4;
  int*   active_list = (int*)(w + off); off += MM*4;
  float* s_vec    = (float*)(w + off); off += BB*DD*4;
  float* coarse_s = (float*)(w + off); off += 256;
  float* spk_ctx  = (float*)(w + off); off += BB*DD*4;
  float* coarse_part = (float*)(w + off); off += 64*4;
  unsigned* counter = (unsigned*)(w + off); off += 256;

  hipMemsetAsync(counter, 0, 4, stream);
  prep1_kernel<<<64, 512, 0, stream>>>(spk_e, spk_W, spk_b, spk_ctx);
  prep2_kernel<<<64, 512, 0, stream>>>(spk_ctx, rW1, cW1, cb1, cW2, grate,
                                       s_vec, coarse_part);
  prep3_kernel<<<1, 64, 0, stream>>>(coarse_part, cb2, coarse_s);
  transpose_kernel<<<dim3(8,8), dim3(64,8), 0, stream>>>(rW1, wsWqT);
  scan_kernel<<<BB, 512, 0, stream>>>(la, um, smk, zm, stab, lre, grate, coarse_s,
      rate_seq, gterm_a, rgate_a, active_list, counter, (float*)d_out);
  build_q_kernel<<<512, 512, 0, stream>>>(content, la, sep, edge, emb, fW, fb,
      rate_seq, active_list, counter, wsQ);
  gemm_kernel<<<MM/32, 512, 0, stream>>>(wsQ, wsWqT, s_vec, rW1, rb1, rW2, rb2,
      gterm_a, rgate_a, active_list, counter, (float*)d_out);
}

// Round 6
// 49.973 us; speedup vs baseline: 4.2626x; 1.0600x over previous
//
#include <hip/hip_runtime.h>
#include <hip/hip_bf16.h>

// ---- problem constants ----
#define BB 8
#define TT 4096
#define DD 512
#define MM (BB*TT)          // 32768 rows
#define DECAYF 0.95f
#define OMDECAYF (1.0f - 0.95f)

typedef __attribute__((ext_vector_type(8))) short bf16x8;
typedef __attribute__((ext_vector_type(4))) float f32x4;

__device__ __forceinline__ float gelu_f(float x){
  return 0.5f * x * (1.0f + erff(x * 0.70710678118654752f));
}

__device__ __forceinline__ unsigned short f2bf(float x){
  unsigned u = __float_as_uint(x);
  unsigned r = (u + 0x7FFFu + ((u >> 16) & 1u)) >> 16;
  return (unsigned short)r;
}

// =============== K1: prep1 (blocks 0-63) + transpose (blocks 64-127) + zero ===
__global__ __launch_bounds__(512) void fused1_kernel(
    const float* __restrict__ spk_embed, const float* __restrict__ spk_W,
    const float* __restrict__ spk_b, float* __restrict__ spk_ctx,
    const float* __restrict__ rW1, unsigned short* __restrict__ wqt,
    unsigned* __restrict__ counter)
{
  __shared__ float se[DD];
  __shared__ float red[8][64];
  __shared__ float tile[64][65];
  int blk = blockIdx.x, t = threadIdx.x;
  if (blk < 64){
    // ---- prep1: spk_ctx = tanh(spk_embed @ spk_W + spk_b) ----
    int b = blk >> 3, d0 = (blk & 7) * 64;
    int dl = t & 63, ks = t >> 6;
    se[t] = spk_embed[b*DD + t];
    __syncthreads();
    float a = 0.f;
    const float* wp = spk_W + (long)(ks*64)*DD + d0 + dl;
    #pragma unroll 8
    for (int k = 0; k < 64; ++k) a += se[ks*64 + k] * wp[(long)k*DD];
    red[ks][dl] = a;
    __syncthreads();
    if (t < 64){
      float s = spk_b[d0 + t];
      #pragma unroll
      for (int i = 0; i < 8; ++i) s += red[i][t];
      spk_ctx[b*DD + d0 + t] = tanhf(s);
    }
  } else {
    // ---- transpose Wq (k-major f32) -> WqT (n-major bf16) ----
    if (blk == 64 && t == 0) *counter = 0;
    int tb = blk - 64;
    int nb = (tb & 7) * 64, kb = (tb >> 3) * 64;
    int tx = t & 63, ty = t >> 6;
    #pragma unroll
    for (int i = 0; i < 8; ++i){
      int k = ty + i*8;
      tile[k][tx] = rW1[(long)(kb + k)*DD + nb + tx];
    }
    __syncthreads();
    #pragma unroll
    for (int i = 0; i < 8; ++i){
      int nl = ty + i*8;
      wqt[(long)(nb + nl)*DD + kb + tx] = f2bf(tile[tx][nl]);
    }
  }
}

// =============== K2: s_vec = spk_ctx@Ws ; coarse hidden partial dot ===============
__global__ __launch_bounds__(512) void prep2_kernel(
    const float* __restrict__ spk_ctx, const float* __restrict__ rW1,
    const float* __restrict__ cW1, const float* __restrict__ cb1,
    const float* __restrict__ cW2, const float* __restrict__ grate,
    float* __restrict__ s_vec, float* __restrict__ coarse_part)
{
  __shared__ float sc[DD];
  __shared__ float red1[8][64];
  __shared__ float red2[8][64];
  int blk = blockIdx.x;
  int b = blk >> 3, d0 = (blk & 7) * 64;
  int t = threadIdx.x, dl = t & 63, ks = t >> 6;
  sc[t] = spk_ctx[b*DD + t];
  __syncthreads();
  float a1 = 0.f, a2 = 0.f;
  const float* wsp = rW1 + (long)(DD + ks*64)*DD + d0 + dl;   // Ws = res_W1[D:2D]
  const float* wcp = cW1 + (long)(ks*64)*DD + d0 + dl;
  #pragma unroll 4
  for (int k = 0; k < 64; ++k){
    float s = sc[ks*64 + k];
    a1 += s * wsp[(long)k*DD];
    a2 += s * wcp[(long)k*DD];
  }
  red1[ks][dl] = a1; red2[ks][dl] = a2;
  __syncthreads();
  if (t < 64){
    int d = d0 + t;
    float s1 = 0.f;
    float s2 = cb1[d] + grate[b] * cW1[(long)DD*DD + d];   // row 512 = grc coeff
    #pragma unroll
    for (int i = 0; i < 8; ++i){ s1 += red1[i][t]; s2 += red2[i][t]; }
    s_vec[b*DD + d] = s1;
    float hv = gelu_f(s2) * cW2[d];
    #pragma unroll
    for (int sh = 1; sh < 64; sh <<= 1) hv += __shfl_xor(hv, sh, 64);
    if (t == 0) coarse_part[blk] = hv;
  }
}

// === K3: fused scan: rate + gterm/rgate + baseline out + active compaction ===
// one block per batch; 512 threads x 8 elements
__global__ __launch_bounds__(512) void scan_kernel(
    const float* __restrict__ la_g, const int* __restrict__ um,
    const int* __restrict__ sm, const int* __restrict__ zm,
    const float* __restrict__ stab_g, const float* __restrict__ lre,
    const float* __restrict__ grate, const float* __restrict__ coarse_part,
    const float* __restrict__ cb2,
    float* __restrict__ rate_seq, float* __restrict__ gterm_a,
    float* __restrict__ rgate_a, int* __restrict__ active_list,
    unsigned* __restrict__ counter, float* __restrict__ out)
{
  __shared__ float wAg[8], wBg[8], wSg[8];
  int b = blockIdx.x, t = threadIdx.x;
  int lane = t & 63, wid = t >> 6;
  int base = b*TT + t*8;

  // coarse scalar (deterministic fixed-order sum of the 8 partials)
  float csum = cb2[0];
  #pragma unroll
  for (int c = 0; c < 8; ++c) csum += coarse_part[b*8 + c];
  float cs = 0.2f * tanhf(csum);

  float4 la0 = *(const float4*)(la_g + base);
  float4 la1 = *(const float4*)(la_g + base + 4);
  int4 u0 = *(const int4*)(um + base), u1 = *(const int4*)(um + base + 4);
  int4 s0 = *(const int4*)(sm + base), s1 = *(const int4*)(sm + base + 4);
  int4 z0 = *(const int4*)(zm + base), z1 = *(const int4*)(zm + base + 4);
  float4 st0 = *(const float4*)(stab_g + base), st1 = *(const float4*)(stab_g + base + 4);
  float lav[8] = {la0.x,la0.y,la0.z,la0.w,la1.x,la1.y,la1.z,la1.w};
  int uv[8] = {u0.x,u0.y,u0.z,u0.w,u1.x,u1.y,u1.z,u1.w};
  int sv[8] = {s0.x,s0.y,s0.z,s0.w,s1.x,s1.y,s1.z,s1.w};
  int zv[8] = {z0.x,z0.y,z0.z,z0.w,z1.x,z1.y,z1.z,z1.w};
  float stv_[8] = {st0.x,st0.y,st0.z,st0.w,st1.x,st1.y,st1.z,st1.w};
  float spv[8], cmv[8], slv[8], stv[8];

  float A = 1.f, Bv = 0.f, S = 0.f;
  #pragma unroll
  for (int i = 0; i < 8; ++i){
    float m = uv[i] > 0 ? 1.f : 0.f;
    float sealed = sv[i] > 0 ? 1.f : 0.f;
    float sil = (zv[i] > 0 ? 1.f : 0.f) * m;
    float commit = m * sealed;
    float speech = commit * (1.f - sil);
    spv[i] = speech; cmv[i] = commit; slv[i] = commit * sil;
    stv[i] = fminf(fmaxf(stv_[i], 0.f), 1.f) * m;
    if (speech > 0.f){
      Bv = DECAYF*Bv + OMDECAYF*lav[i];
      A *= DECAYF;
      S += 1.f;
    }
  }
  // wave-inclusive scan (lane order = time order)
  #pragma unroll
  for (int d = 1; d < 64; d <<= 1){
    float Au = __shfl_up(A, d, 64);
    float Bu = __shfl_up(Bv, d, 64);
    float Su = __shfl_up(S, d, 64);
    if (lane >= d){ Bv = A*Bu + Bv; A = A*Au; S += Su; }
  }
  if (lane == 63){ wAg[wid] = A; wBg[wid] = Bv; wSg[wid] = S; }
  float Ale = __shfl_up(A, 1, 64), Ble = __shfl_up(Bv, 1, 64), Sle = __shfl_up(S, 1, 64);
  if (lane == 0){ Ale = 1.f; Ble = 0.f; Sle = 0.f; }
  __syncthreads();
  float Awp = 1.f, Bwp = 0.f, Swp = 0.f;
  for (int w = 0; w < wid; ++w){
    Bwp = wAg[w]*Bwp + wBg[w];
    Awp = wAg[w]*Awp;
    Swp += wSg[w];
  }
  float Bex = Ale*Bwp + Ble;
  float Aex = Ale*Awp;
  float Sex = Swp + Sle;

  float rate = Aex*lre[b] + Bex;
  float ps = Sex;
  float grc = grate[b];
  float ro[8], go[8], rg[8], oo[8];
  #pragma unroll
  for (int i = 0; i < 8; ++i){
    ro[i] = rate;
    float g = (grc - rate + cs) * cmv[i];
    float cold = fminf(ps * 0.5f, 1.f);                       // COLD_RUNS=2
    float shortg = fminf(fmaxf(expf(lav[i]) - 1.f, 0.f), 1.f); // MIN_DUR=2
    float rgv = cold * shortg * stv[i] * spv[i];
    go[i] = g; rg[i] = rgv;
    oo[i] = fminf(fmaxf(g, -1.2f), 1.2f) * spv[i]
          + fminf(fmaxf(g, -0.35f), 0.35f) * slv[i];
    if (spv[i] > 0.f){
      rate = DECAYF*rate + OMDECAYF*lav[i];
      ps += 1.f;
    }
  }
  *(float4*)(rate_seq + base)     = make_float4(ro[0],ro[1],ro[2],ro[3]);
  *(float4*)(rate_seq + base + 4) = make_float4(ro[4],ro[5],ro[6],ro[7]);
  *(float4*)(gterm_a + base)      = make_float4(go[0],go[1],go[2],go[3]);
  *(float4*)(gterm_a + base + 4)  = make_float4(go[4],go[5],go[6],go[7]);
  *(float4*)(rgate_a + base)      = make_float4(rg[0],rg[1],rg[2],rg[3]);
  *(float4*)(rgate_a + base + 4)  = make_float4(rg[4],rg[5],rg[6],rg[7]);
  *(float4*)(out + base)          = make_float4(oo[0],oo[1],oo[2],oo[3]);
  *(float4*)(out + base + 4)      = make_float4(oo[4],oo[5],oo[6],oo[7]);

  // --- compaction: append active row indices (rgate != 0) ---
  int nact = 0;
  #pragma unroll
  for (int i = 0; i < 8; ++i) nact += (rg[i] != 0.f) ? 1 : 0;
  int inc = nact;
  #pragma unroll
  for (int d = 1; d < 64; d <<= 1){
    int u = __shfl_up(inc, d, 64);
    if (lane >= d) inc += u;
  }
  int myex = inc - nact;
  unsigned ub = 0;
  if (lane == 63) ub = atomicAdd(counter, (unsigned)inc);
  ub = (unsigned)__shfl((int)ub, 63, 64);
  int pos = (int)ub + myex;
  #pragma unroll
  for (int i = 0; i < 8; ++i){
    if (rg[i] != 0.f) active_list[pos++] = base + i;
  }
}

// =============== K4: fused Q-build + GEMM + epilogue on ACTIVE rows ===========
// BM=32, BN=512 (full N -> row-dot block-local), BK=32, 8 waves x (32x64)
// A tile built in-kernel into LDS: Af[kc][row][64B], slot ^ ((row>>1)&3) swizzle
__global__ __launch_bounds__(512) void gemm_kernel(
    const int* __restrict__ content, const float* __restrict__ la_g,
    const float* __restrict__ sep, const float* __restrict__ edge,
    const float* __restrict__ emb, const float* __restrict__ fW,
    const float* __restrict__ fb, const float* __restrict__ rate_seq,
    const unsigned short* __restrict__ wqt,
    const float* __restrict__ s_vec, const float* __restrict__ rW1,
    const float* __restrict__ rb1, const float* __restrict__ rW2,
    const float* __restrict__ rb2,
    const float* __restrict__ gterm_a, const float* __restrict__ rgate_a,
    const int* __restrict__ active_list, const unsigned* __restrict__ counter,
    float* __restrict__ out)
{
  __shared__ unsigned short Af[16*32*32];    // [kc][row][32k] = 32 KB
  __shared__ unsigned short Bs[2][512*32];   // 64 KB
  __shared__ float part[8][32];              // 1 KB
  int tid = threadIdx.x, wid = tid >> 6, lane = tid & 63;
  int cnt = (int)*counter;
  int r0 = blockIdx.x * 32;
  if (r0 >= cnt) return;
  const char* wbase = (const char*)wqt;

  auto stageB = [&](int buf, int kc){
    int k0b = kc * 64;  // byte offset into each 1024B (512-elem bf16) row
    #pragma unroll
    for (int i = 0; i < 4; ++i){
      int j = wid*4 + i;                      // 32 wave-issues for 512 n-rows
      int n = j*16 + (lane >> 2);
      int slot = (lane & 3) ^ ((n >> 1) & 3);
      const char* src = wbase + (long)n*1024 + k0b + slot*16;
      char* dst = (char*)&Bs[buf][0] + j*1024 + (lane << 4);
      __builtin_amdgcn_global_load_lds(
          (const __attribute__((address_space(1))) void*)src,
          (__attribute__((address_space(3))) void*)dst, 16, 0, 0);
    }
  };

  stageB(0, 0);

  // ---- build A tile: thread -> row rr = tid>>4, k-chunk kc = tid&15 ----
  {
    int rr = tid >> 4, kc = tid & 15;
    int p = r0 + rr; if (p > cnt-1) p = cnt-1;
    int gr = active_list[p];
    float la = la_g[gr], rate = rate_seq[gr];
    float sepv = sep[gr], edgev = edge[gr];
    int k0 = kc * 32;
    const float* er = emb + (long)content[gr]*DD + k0;
    union { bf16x8 v[4]; unsigned short h[32]; } pk;
    #pragma unroll
    for (int i = 0; i < 32; i += 4){
      float4 e  = *(const float4*)(er + i);
      float4 w0 = *(const float4*)(fW + 0*DD + k0 + i);
      float4 w1 = *(const float4*)(fW + 1*DD + k0 + i);
      float4 w3 = *(const float4*)(fW + 3*DD + k0 + i);
      float4 w4 = *(const float4*)(fW + 4*DD + k0 + i);
      float4 bb = *(const float4*)(fb + k0 + i);
      pk.h[i+0] = f2bf(gelu_f(e.x + la*w0.x + rate*w1.x + sepv*w3.x + edgev*w4.x + bb.x));
      pk.h[i+1] = f2bf(gelu_f(e.y + la*w0.y + rate*w1.y + sepv*w3.y + edgev*w4.y + bb.y));
      pk.h[i+2] = f2bf(gelu_f(e.z + la*w0.z + rate*w1.z + sepv*w3.z + edgev*w4.z + bb.z));
      pk.h[i+3] = f2bf(gelu_f(e.w + la*w0.w + rate*w1.w + sepv*w3.w + edgev*w4.w + bb.w));
    }
    int c = (rr >> 1) & 3;
    char* abase = (char*)Af + kc*2048 + rr*64;
    #pragma unroll
    for (int s = 0; s < 4; ++s)
      *(bf16x8*)(abase + ((s ^ c) << 4)) = pk.v[s];
  }
  __syncthreads();   // Af built AND Bs[0] landed (vmcnt drained by barrier)

  f32x4 acc[2][4];
  #pragma unroll
  for (int i = 0; i < 2; ++i)
    #pragma unroll
    for (int j = 0; j < 4; ++j) acc[i][j] = (f32x4){0.f,0.f,0.f,0.f};

  int rgp = lane >> 4, li = lane & 15;
  for (int kc = 0; kc < 16; ++kc){
    int cur = kc & 1;
    if (kc < 15) stageB(cur ^ 1, kc + 1);
    bf16x8 a[2], bb[4];
    #pragma unroll
    for (int mt = 0; mt < 2; ++mt){
      int row = mt*16 + li;
      int slot = rgp ^ ((row >> 1) & 3);
      a[mt] = *(const bf16x8*)((const char*)Af + kc*2048 + row*64 + (slot << 4));
    }
    #pragma unroll
    for (int nt = 0; nt < 4; ++nt){
      int n = wid*64 + nt*16 + li;
      int slot = rgp ^ ((n >> 1) & 3);
      bb[nt] = *(const bf16x8*)((const char*)&Bs[cur][0] + n*64 + slot*16);
    }
    #pragma unroll
    for (int mt = 0; mt < 2; ++mt)
      #pragma unroll
      for (int nt = 0; nt < 4; ++nt)
        acc[mt][nt] = __builtin_amdgcn_mfma_f32_16x16x32_bf16(a[mt], bb[nt], acc[mt][nt], 0, 0, 0);
    __syncthreads();
  }

  // epilogue: h = gelu(y + s_vec[b] + gterm*wg + b1); partial dot with res_W2
  float wgv[4], b1v[4], w2v[4];
  #pragma unroll
  for (int nt = 0; nt < 4; ++nt){
    int j = wid*64 + nt*16 + li;
    wgv[nt] = rW1[1024*DD + j];    // wg = res_W1 row 1024
    b1v[nt] = rb1[j];
    w2v[nt] = rW2[j];
  }
  #pragma unroll
  for (int mt = 0; mt < 2; ++mt){
    #pragma unroll
    for (int r = 0; r < 4; ++r){
      int row = mt*16 + rgp*4 + r;
      int p = r0 + row; if (p > cnt-1) p = cnt-1;
      int gr = active_list[p];
      int b = gr >> 12;
      float gt = gterm_a[gr];
      float s = 0.f;
      #pragma unroll
      for (int nt = 0; nt < 4; ++nt){
        int j = wid*64 + nt*16 + li;
        float y = acc[mt][nt][r] + s_vec[b*DD + j] + gt*wgv[nt] + b1v[nt];
        s += gelu_f(y) * w2v[nt];
      }
      s += __shfl_xor(s, 1, 64);
      s += __shfl_xor(s, 2, 64);
      s += __shfl_xor(s, 4, 64);
      s += __shfl_xor(s, 8, 64);
      if (li == 0) part[wid][row] = s;
    }
  }
  __syncthreads();
  if (tid < 32){
    int p = r0 + tid;
    if (p < cnt){
      int gr = active_list[p];
      float s = 0.f;
      #pragma unroll
      for (int w = 0; w < 8; ++w) s += part[w][tid];
      float resid = 0.35f * tanhf(s + rb2[0]) * rgate_a[gr];
      float g = gterm_a[gr];
      // active rows: speech==1, sil_commit==0
      out[gr] = fminf(fmaxf(g + resid, -1.2f), 1.2f);
    }
  }
}

extern "C" void kernel_launch(void* const* d_in, const int* in_sizes, int n_in,
                              void* d_out, int out_size, void* d_ws, size_t ws_size,
                              hipStream_t stream)
{
  const int*   content = (const int*)  d_in[0];
  const float* la      = (const float*)d_in[1];
  const int*   um      = (const int*)  d_in[2];
  const int*   smk     = (const int*)  d_in[3];
  const int*   zm      = (const int*)  d_in[4];
  const float* sep     = (const float*)d_in[5];
  const float* edge    = (const float*)d_in[6];
  const float* stab    = (const float*)d_in[7];
  const float* grate   = (const float*)d_in[8];
  const float* lre     = (const float*)d_in[9];
  const float* spk_e   = (const float*)d_in[10];
  const float* emb     = (const float*)d_in[11];
  const float* fW      = (const float*)d_in[12];
  const float* fb      = (const float*)d_in[13];
  const float* spk_W   = (const float*)d_in[14];
  const float* spk_b   = (const float*)d_in[15];
  const float* cW1     = (const float*)d_in[16];
  const float* cb1     = (const float*)d_in[17];
  const float* cW2     = (const float*)d_in[18];
  const float* cb2     = (const float*)d_in[19];
  const float* rW1     = (const float*)d_in[20];
  const float* rb1     = (const float*)d_in[21];
  const float* rW2     = (const float*)d_in[22];
  const float* rb2     = (const float*)d_in[23];

  char* w = (char*)d_ws;
  unsigned short* wsWqT = (unsigned short*)(w);                 // 524288 B
  size_t off = 524288;
  float* rate_seq = (float*)(w + off); off += MM*4;
  float* gterm_a  = (float*)(w + off); off += MM*4;
  float* rgate_a  = (float*)(w + off); off += MM*4;
  int*   active_list = (int*)(w + off); off += MM*4;
  float* s_vec    = (float*)(w + off); off += BB*DD*4;
  float* spk_ctx  = (float*)(w + off); off += BB*DD*4;
  float* coarse_part = (float*)(w + off); off += 64*4;
  unsigned* counter = (unsigned*)(w + off); off += 256;

  fused1_kernel<<<128, 512, 0, stream>>>(spk_e, spk_W, spk_b, spk_ctx,
                                         rW1, wsWqT, counter);
  prep2_kernel<<<64, 512, 0, stream>>>(spk_ctx, rW1, cW1, cb1, cW2, grate,
                                       s_vec, coarse_part);
  scan_kernel<<<BB, 512, 0, stream>>>(la, um, smk, zm, stab, lre, grate,
      coarse_part, cb2, rate_seq, gterm_a, rgate_a, active_list, counter,
      (float*)d_out);
  gemm_kernel<<<MM/32, 512, 0, stream>>>(content, la, sep, edge, emb, fW, fb,
      rate_seq, wsWqT, s_vec, rW1, rb1, rW2, rb2,
      gterm_a, rgate_a, active_list, counter, (float*)d_out);
}